// Round 6
// baseline (537.554 us; speedup 1.0000x reference)
//
#include <hip/hip_runtime.h>
#include <stdint.h>

#define HW    16384
#define NB    64
#define W2    130           // padded spatial dim (1-px halo each side)
#define PXS   (W2*W2)       // 16900 pixels per padded plane
#define WQH   70144         // fp16 weight halves per sample (frag-ordered)
#define EPSB  1e-5f
#define GP    1444          // px per LDS granule-plane (38*38)
#define GPB   23104         // bytes per granule-plane (GP*16)
#define ROWB  608           // bytes per row within a granule-plane (38*16)
#define PLH   34656         // halves per LDS plane (3 granules * 1444 * 8)
#define NTH   768           // stage3 threads (12 waves -> 3 waves/SIMD)
#define NWV   12

typedef _Float16 h8  __attribute__((ext_vector_type(8)));
typedef _Float16 h4  __attribute__((ext_vector_type(4)));
typedef float    f16v __attribute__((ext_vector_type(16)));
typedef float    f4  __attribute__((ext_vector_type(4)));
typedef h8 uh8 __attribute__((aligned(4)));
typedef h4 uh4 __attribute__((aligned(4)));
typedef f4 uf4 __attribute__((aligned(4)));

// ---------------------------------------------------------------------------
// prep_w: gather per-sample hypernet weights, fold BN scale, convert fp16,
// and write in EXACT mfma_32x32x16_f16 A-fragment order:
//   per layer, frame f = (tap*KST + kstep); within frame, lane(0..63) holds
//   8 halves: w[co = lane&31][c = kstep*16 + (lane>>5)*8 + e]  (0-padded).
// Frames/layer: L0-2: 9, L3-8: 18, L9(1x1): 2.
// Also emits fp32 bias[l*32+co] = beta - mu*scale (0 for padded co / L9).
// ---------------------------------------------------------------------------
__global__ void prep_w(const float* __restrict__ w1, const float* __restrict__ w2,
                       const float* __restrict__ w3, const float* __restrict__ w4,
                       const float* __restrict__ g,  const float* __restrict__ be,
                       const float* __restrict__ mu, const float* __restrict__ va,
                       _Float16* __restrict__ wq, float* __restrict__ bias)
{
    const int FO[11]   = {0,576,1152,1728,2880,4032,5184,6336,7488,8640,8768};
    const int start[10]= {0,1080,2376,3672,8424,13608,16200,20952,26136,28728};
    const int COt[10]  = {12,12,12,24,24,12,24,24,12,11};
    const int CIt[10]  = {10,12,12,22,24,24,22,24,24,22};
    const int bnoff[10]= {0,12,24,36,60,84,96,120,144,0};
    const int KST[10]  = {1,1,1,2,2,2,2,2,2,2};

    long tid = (long)blockIdx.x * 256 + threadIdx.x;
    long total = (long)NB * 8768, stride = (long)gridDim.x * 256;
    for (long idx = tid; idx < total; idx += stride) {
        int b = (int)(idx / 8768), i = (int)(idx - (long)b * 8768);
        int l = 9; while (i < FO[l]) --l;
        int j = i - FO[l];
        int f = j >> 6, lane = j & 63;
        int ks = (KST[l] == 2) ? (f & 1) : 0;
        int s  = (KST[l] == 2) ? (f >> 1) : f;      // 3x3 tap index (0 for L9)
        int co = lane & 31, hi = lane >> 5;
        int CO = COt[l], CI = CIt[l];
        float scale = 1.f;
        if (l < 9 && co < CO) {
            int bi = bnoff[l] + co;
            scale = g[bi] * rsqrtf(va[bi] + EPSB);
        }
        int c0 = ks * 16 + hi * 8;
        __attribute__((aligned(16))) _Float16 vals[8];
#pragma unroll
        for (int e = 0; e < 8; ++e) {
            int c = c0 + e; float wv = 0.f;
            if (co < CO && c < CI) {
                int p = (l < 9) ? start[l] + (co * CI + c) * 9 + s
                                : start[9] + co * CI + c;
                const float* src; long si;
                if      (p <  3672) { src = w1; si = (long)b *  3672 + p; }
                else if (p < 16200) { src = w2; si = (long)b * 12528 + (p -  3672); }
                else if (p < 28728) { src = w3; si = (long)b * 12528 + (p - 16200); }
                else                { src = w4; si = (long)b *   242 + (p - 28728); }
                wv = src[si] * scale;
            }
            vals[e] = (_Float16)wv;
        }
        *(uh8*)(wq + idx * 8) = *(const h8*)vals;
    }
    if (tid < 320) {
        int l = (int)tid >> 5, co = (int)tid & 31;
        float v = 0.f;
        if (l < 9 && co < COt[l]) {
            int bi = bnoff[l] + co;
            float sc = g[bi] * rsqrtf(va[bi] + EPSB);
            v = be[bi] - mu[bi] * sc;
        }
        bias[tid] = v;
    }
}

// ---------------------------------------------------------------------------
// pad_x: init both NHWC 32-ch fp16 buffers for a chunk.
//   bufA: ch0-9 = x, ch10-11 = 0, ch12-21 = x, ch22-31 = 0  (stage1 input)
//   bufB: ch12-21 = x, rest 0                                (skip-concat copy)
// Borders and all unused channels zeroed.
// ---------------------------------------------------------------------------
__global__ void pad_x(const float* __restrict__ x, _Float16* __restrict__ bufA,
                      _Float16* __restrict__ bufB, int b0)
{
    int sl = blockIdx.x >> 3, part = blockIdx.x & 7;
    int gb = b0 + sl;
    const float* __restrict__ xs = x + (long)gb * 10 * HW;
    _Float16* __restrict__ dA = bufA + (long)sl * PXS * 32;
    _Float16* __restrict__ dB = bufB + (long)sl * PXS * 32;
    for (int p = part * 256 + threadIdx.x; p < PXS; p += 2048) {
        int r = p / W2, cc = p - r * W2;
        __attribute__((aligned(16))) _Float16 pxA[32], pxB[32];
#pragma unroll
        for (int i = 0; i < 32; ++i) { pxA[i] = (_Float16)0.f; pxB[i] = (_Float16)0.f; }
        if (r >= 1 && r <= 128 && cc >= 1 && cc <= 128) {
            int so = (r - 1) * 128 + (cc - 1);
#pragma unroll
            for (int c = 0; c < 10; ++c) {
                _Float16 xv = (_Float16)xs[c * HW + so];
                pxA[c] = xv; pxA[12 + c] = xv; pxB[12 + c] = xv;
            }
        }
        _Float16* ap = dA + (long)p * 32;
        _Float16* bp = dB + (long)p * 32;
#pragma unroll
        for (int q = 0; q < 4; ++q) {
            *(uh8*)(ap + q * 8) = *(const h8*)(pxA + q * 8);
            *(uh8*)(bp + q * 8) = *(const h8*)(pxB + q * 8);
        }
    }
}

// ---------------------------------------------------------------------------
// lconv: one 3x3 conv layer, LDS plane -> LDS plane (SoA granule layout).
// Plane = 3 granule-planes [ch-octet g][38*38 px] x 16B: lane-consecutive
// px -> consecutive 16B addresses -> conflict-free ds_read_b128/ds_write.
// All 30 reads of a unit share ONE VGPR base; offsets are compile-time
// immediates (ks*2*GPB + kc*16 + j*ROWB < 64K).
// Unit = NR output rows x 32 px; r0 clamped so every unit's NR rows are
// valid (tail units overlap-recompute identical rows -> benign).
// Register double-buffer: group g+1's B/A frags load during group g's MFMAs.
// Pad positions (outside global interior) stored as ZERO (reference padding).
// ---------------------------------------------------------------------------
template<int KST, int NR>
__device__ __forceinline__ void lconv(const char* pin, char* pout,
    const _Float16* wl, const float* __restrict__ bias, int boff,
    int rowStart, int nRows, int colStart, int width,
    int oy0, int ox0, int w, int lo5, int hi)
{
    constexpr int qmax = (KST == 1) ? 2 : 3;   // store ch0-15 / ch0-23
    f4 bv[qmax];
#pragma unroll
    for (int q = 0; q < qmax; ++q) bv[q] = *(const uf4*)(bias + boff + hi * 4 + q * 8);

    constexpr int NG = 3 * KST;
    const int ncb = (width > 32) ? 2 : 1;
    const int nrg = (nRows + NR - 1) / NR;
    const int nu  = nrg * ncb;
#pragma unroll 1
    for (int u = w; u < nu; u += NWV) {
        int rg, cb;
        if (ncb == 2) { rg = u >> 1; cb = u & 1; } else { rg = u; cb = 0; }
        int r0 = rowStart + rg * NR;
        { int rmax = rowStart + nRows - NR; r0 = (r0 > rmax) ? rmax : r0; }
        const int cs   = cb ? (colStart + width - 32) : colStart;
        const int cmin = cb ? (64 - width) : 0;
        // one base per unit; every read is base + compile-time offset
        const char* bin = pin + (long)hi * GPB
                        + ((long)(r0 - 1) * 38 + (cs - 1 + lo5)) * 16;

        f16v acc[NR];
        { f16v z = {};
#pragma unroll
          for (int i = 0; i < NR; ++i) acc[i] = z; }

        h8 bf[2][NR + 2];
        h8 af[2][3];
        // prologue: group 0 = (kc=0, ks=0) - never guarded (ks=0)
#pragma unroll
        for (int j = 0; j < NR + 2; ++j)
            bf[0][j] = *(const uh8*)(bin + j * ROWB);
#pragma unroll
        for (int kr = 0; kr < 3; ++kr)
            af[0][kr] = *(const uh8*)(wl + (kr * 3 * KST) * 512);

#pragma unroll
        for (int g = 0; g < NG; ++g) {
            const int cur = g & 1, nxt = cur ^ 1;
            if (g + 1 < NG) {                      // prefetch next group
                const int kc2 = (g + 1) / KST, ks2 = (g + 1) - kc2 * KST;
#pragma unroll
                for (int j = 0; j < NR + 2; ++j) {
                    h8 v = {};
                    if (!(ks2 & hi))               // granule 3 (ci24-31) = 0
                        v = *(const uh8*)(bin + ks2 * 2 * GPB + kc2 * 16 + j * ROWB);
                    bf[nxt][j] = v;
                }
#pragma unroll
                for (int kr = 0; kr < 3; ++kr)
                    af[nxt][kr] = *(const uh8*)(wl + ((kr * 3 + kc2) * KST + ks2) * 512);
            }
#pragma unroll
            for (int kr = 0; kr < 3; ++kr)
#pragma unroll
                for (int tt = 0; tt < NR; ++tt)
                    acc[tt] = __builtin_amdgcn_mfma_f32_32x32x16_f16(
                                  af[cur][kr], bf[cur][kr + tt], acc[tt], 0, 0, 0);
        }

        // epilogue: bias + ReLU + fp16 store (SoA granules, conflict-free)
        const bool cok = (lo5 >= cmin);
        const int  pc  = cs + lo5;
        const int  gx  = ox0 - 3 + pc;
        const bool xin = (unsigned)(gx - 1) < 128u;
        char* pob = pout + (long)hi * 8 + ((long)r0 * 38 + pc) * 16;
        if (cok) {
#pragma unroll
            for (int tt = 0; tt < NR; ++tt) {
                int gy = oy0 - 3 + r0 + tt;
                bool ok = xin && ((unsigned)(gy - 1) < 128u);
#pragma unroll
                for (int q = 0; q < qmax; ++q) {
                    float v0 = ok ? fmaxf(acc[tt][4*q+0] + bv[q][0], 0.f) : 0.f;
                    float v1 = ok ? fmaxf(acc[tt][4*q+1] + bv[q][1], 0.f) : 0.f;
                    float v2 = ok ? fmaxf(acc[tt][4*q+2] + bv[q][2], 0.f) : 0.f;
                    float v3 = ok ? fmaxf(acc[tt][4*q+3] + bv[q][3], 0.f) : 0.f;
                    h4 hv = { (_Float16)v0, (_Float16)v1, (_Float16)v2, (_Float16)v3 };
                    *(uh4*)(pob + q * GPB + tt * ROWB) = hv;
                }
            }
        }
    }
}

// ---------------------------------------------------------------------------
// stage3: fused 3-conv stage, 768 threads (12 waves, 3/SIMD; 1 block/CU due
// to 138.6KB LDS). Per block: one 32x32 output tile of one sample.
//  1) stage 38x38 px x ch0-23 from global NHWC (64B/px) into LDS plane S
//     (SoA granules; lane-consecutive 16B writes, conflict-free).
//  2) conv A: S->T (36x36), conv B: T->S (34x34), conv C: S->T (32x32),
//     all NR=3 (A/B: 24 units = 2/wave exact; C: 11 units), barriers between.
//  3) write T's 32x32 interior, ch0-11 only, to global out (skip-concat:
//     x at ch12-21 of out buffer is preserved).
// ---------------------------------------------------------------------------
template<int KST>
__global__ __launch_bounds__(NTH)
void stage3(const _Float16* __restrict__ in, _Float16* __restrict__ out,
            const _Float16* __restrict__ wq, int loff0,
            const float* __restrict__ bias, int boff0, int b0)
{
    __shared__ _Float16 lds[2][PLH];
    const int t = threadIdx.x, w = t >> 6, l = t & 63;
    const int lo5 = l & 31, hi = l >> 5;

    const int nbb = (int)(gridDim.x >> 4);
    int s, tile;
    if ((nbb & 7) == 0) {                       // XCD-localize each sample
        int xcd = (int)(blockIdx.x & 7), j = (int)(blockIdx.x >> 3);
        s = xcd * (nbb >> 3) + (j >> 4); tile = j & 15;
    } else { s = (int)(blockIdx.x >> 4); tile = (int)(blockIdx.x & 15); }
    const int gb  = b0 + s;
    const int oy0 = 1 + (tile >> 2) * 32;       // padded-coord tile origin
    const int ox0 = 1 + (tile & 3) * 32;

    // ---- 1) stage input window: 3 granules x 1444 px = 4332 x 16B
    {
        const char* src = (const char*)(in + (long)s * PXS * 32);
        char* dst = (char*)&lds[0][0];
        h8 stg[6];
#pragma unroll
        for (int k = 0; k < 6; ++k) {
            int idx = k * NTH + t;
            int g = idx / GP, p = idx - g * GP;
            int r = p / 38, c = p - r * 38;
            int gy = oy0 - 3 + r, gx = ox0 - 3 + c;
            h8 v = {};
            if (idx < 3 * GP && (unsigned)gy < 130u && (unsigned)gx < 130u)
                v = *(const uh8*)(src + ((long)gy * W2 + gx) * 64 + g * 16);
            stg[k] = v;
        }
#pragma unroll
        for (int k = 0; k < 6; ++k) {
            int idx = k * NTH + t;
            if (idx < 3 * GP) *(uh8*)(dst + (long)idx * 16) = stg[k];
        }
    }
    __syncthreads();

    // ---- 2) three convs (regions 36 -> 34 -> 32)
    const _Float16* wl = wq + (long)gb * WQH + loff0 + (long)l * 8;
    constexpr int LSTEP = 9 * KST * 512;
    lconv<KST,3>((const char*)lds[0], (char*)lds[1], wl,             bias, boff0,      1, 36, 1, 36, oy0, ox0, w, lo5, hi);
    __syncthreads();
    lconv<KST,3>((const char*)lds[1], (char*)lds[0], wl + LSTEP,     bias, boff0 + 32, 2, 34, 2, 34, oy0, ox0, w, lo5, hi);
    __syncthreads();
    lconv<KST,3>((const char*)lds[0], (char*)lds[1], wl + 2 * LSTEP, bias, boff0 + 64, 3, 32, 3, 32, oy0, ox0, w, lo5, hi);
    __syncthreads();

    // ---- 3) write ch0-11 of the 32x32 interior to global
    {
        _Float16* db = out + (long)s * PXS * 32;
        const char* T = (const char*)&lds[1][0];
#pragma unroll
        for (int k = 0; k < 2; ++k) {
            int px = k * NTH + t;
            if (px < 1024) {
                int pr = 3 + (px >> 5), pc = 3 + (px & 31);
                int gy = oy0 + (px >> 5), gx = ox0 + (px & 31);
                const char* sp = T + ((long)pr * 38 + pc) * 16;
                h8 v0 = *(const uh8*)sp;            // ch0-7
                h4 v1 = *(const uh4*)(sp + GPB);    // ch8-11
                _Float16* dp = db + ((long)gy * W2 + gx) * 32;
                *(uh8*)dp = v0;
                *(uh4*)(dp + 8) = v1;
            }
        }
    }
}

// ---- final 1x1 conv (CIN=22 in bufB, CO=11), fp32 NCHW output, no BN/ReLU.
__global__ __launch_bounds__(256, 2)
void conv1(const _Float16* __restrict__ in, float* __restrict__ outF,
           const _Float16* __restrict__ wq, int loff, int b0)
{
    const int s = blockIdx.y, gb = b0 + s;
    const int t = threadIdx.x, w = t >> 6, l = t & 63;
    const int lo5 = l & 31, hi = l >> 5;
    const int cb = blockIdx.x & 3;
    const int y00 = (blockIdx.x >> 2) * 32 + w * 8;
    const int xpix = cb * 32 + lo5;

    const _Float16* wl = wq + (long)gb * WQH + loff + (long)l * 8;
    h8 a0 = *(const uh8*)(wl);
    h8 a1 = *(const uh8*)(wl + 512);
    const _Float16* ib = in + (long)s * PXS * 32;

#pragma unroll 1
    for (int tt = 0; tt < 8; ++tt) {
        int y = y00 + tt;
        const _Float16* bp = ib + ((long)(y + 1) * W2 + xpix + 1) * 32 + hi * 8;
        h8 bA = *(const uh8*)(bp);
        h8 bB = *(const uh8*)(bp + 16);
        f16v acc = {};
        acc = __builtin_amdgcn_mfma_f32_32x32x16_f16(a0, bA, acc, 0, 0, 0);
        acc = __builtin_amdgcn_mfma_f32_32x32x16_f16(a1, bB, acc, 0, 0, 0);
        long px = (long)y * 128 + xpix;
#pragma unroll
        for (int r = 0; r < 16; ++r) {
            int co = (r & 3) + 8 * (r >> 2) + 4 * hi;
            if (co < 11) outF[((long)gb * 11 + co) * HW + px] = acc[r];
        }
    }
}

extern "C" void kernel_launch(void* const* d_in, const int* in_sizes, int n_in,
                              void* d_out, int out_size, void* d_ws, size_t ws_size,
                              hipStream_t stream)
{
    const float *x = (const float*)d_in[0], *w1 = (const float*)d_in[1],
                *w2 = (const float*)d_in[2], *w3 = (const float*)d_in[3],
                *w4 = (const float*)d_in[4], *g  = (const float*)d_in[5],
                *be = (const float*)d_in[6], *mu = (const float*)d_in[7],
                *va = (const float*)d_in[8];
    if (n_in == 9) {   // identify by size signature (fallback: dict order)
        const float* big801[2] = {nullptr, nullptr}; int n801 = 0;
        const float* bn156[4]  = {nullptr, nullptr, nullptr, nullptr}; int n156 = 0;
        const float *fx = nullptr, *fw1 = nullptr, *fw4 = nullptr;
        for (int i = 0; i < 9; ++i) {
            int sz = in_sizes[i];
            if      (sz == 10485760) fx  = (const float*)d_in[i];
            else if (sz ==   235008) fw1 = (const float*)d_in[i];
            else if (sz ==   801792) { if (n801 < 2) big801[n801++] = (const float*)d_in[i]; }
            else if (sz ==    15488) fw4 = (const float*)d_in[i];
            else if (sz ==      156) { if (n156 < 4) bn156[n156++] = (const float*)d_in[i]; }
        }
        if (fx && fw1 && fw4 && n801 == 2 && n156 == 4) {
            x = fx; w1 = fw1; w2 = big801[0]; w3 = big801[1]; w4 = fw4;
            g = bn156[0]; be = bn156[1]; mu = bn156[2]; va = bn156[3];
        }
    }
    float* out = (float*)d_out;

    // ws: [wq fp16 8.98MB][bias 2KB][bufA | bufB], each 64B/px NHWC padded.
    // chunk=64 needs 9MB + 2*64*1.08MB = 147MB.
    const size_t wqB   = (size_t)NB * WQH * 2;
    const size_t biasB = 2048;
    const size_t hdr   = wqB + biasB;
    const size_t perSlot = (size_t)PXS * 128;   // 2 buffers x 64B/px
    size_t avail = ws_size > hdr ? ws_size - hdr : 0;
    int chunk = (int)(avail / perSlot);
    if (chunk > NB) chunk = NB;
    if (chunk < 1)  chunk = 1;

    _Float16* wq   = (_Float16*)d_ws;
    float*    bias = (float*)((char*)d_ws + wqB);
    _Float16* bufA = (_Float16*)((char*)d_ws + hdr);
    _Float16* bufB = bufA + (size_t)chunk * PXS * 32;

    prep_w<<<2048, 256, 0, stream>>>(w1, w2, w3, w4, g, be, mu, va, wq, bias);

    for (int b0 = 0; b0 < NB; b0 += chunk) {
        int nb = (NB - b0 < chunk) ? (NB - b0) : chunk;
        pad_x<<<nb * 8, 256, 0, stream>>>(x, bufA, bufB, b0);
        int gc = nb * 16;
        dim3 g1(16, nb);
        // stage1: L0-L2 (x @ bufA ch0-9) -> bufB ch0-11
        stage3<1><<<gc, NTH, 0, stream>>>(bufA, bufB, wq,     0, bias,   0, b0);
        // stage2: L3-L5 (bufB: prev@0-11 + x@12-21) -> bufA ch0-11
        stage3<2><<<gc, NTH, 0, stream>>>(bufB, bufA, wq, 13824, bias,  96, b0);
        // stage3: L6-L8 -> bufB ch0-11
        stage3<2><<<gc, NTH, 0, stream>>>(bufA, bufB, wq, 41472, bias, 192, b0);
        // L9: 1x1, 22ch -> 11ch fp32
        conv1<<<g1, 256, 0, stream>>>(bufB, out, wq, 69120, b0);
    }
}

// Round 7
// 530.443 us; speedup vs baseline: 1.0134x; 1.0134x over previous
//
#include <hip/hip_runtime.h>
#include <stdint.h>

#define HW    16384
#define NB    64
#define W2    130           // padded spatial dim (1-px halo each side)
#define PXS   (W2*W2)       // 16900 pixels per padded plane
#define WQH   70144         // fp16 weight halves per sample (frag-ordered)
#define EPSB  1e-5f
#define GP    1444          // px per LDS granule-plane (38*38)
#define GPB   23104         // bytes per granule-plane (GP*16)
#define ROWB  608           // bytes per row within a granule-plane (38*16)
#define PLH   34656         // halves per LDS plane (3 granules * 1444 * 8)
#define NTH   768           // stage3 threads (12 waves -> 3 waves/SIMD)
#define NWV   12

typedef _Float16 h8  __attribute__((ext_vector_type(8)));
typedef _Float16 h4  __attribute__((ext_vector_type(4)));
typedef float    f16v __attribute__((ext_vector_type(16)));
typedef float    f4  __attribute__((ext_vector_type(4)));
typedef h8 uh8 __attribute__((aligned(4)));
typedef h4 uh4 __attribute__((aligned(4)));
typedef f4 uf4 __attribute__((aligned(4)));

// ---------------------------------------------------------------------------
// prep_w: gather per-sample hypernet weights, fold BN scale, convert fp16,
// and write in EXACT mfma_32x32x16_f16 A-fragment order:
//   per layer, frame f = (tap*KST + kstep); within frame, lane(0..63) holds
//   8 halves: w[co = lane&31][c = kstep*16 + (lane>>5)*8 + e]  (0-padded).
// Frames/layer: L0-2: 9, L3-8: 18, L9(1x1): 2.
// Also emits fp32 bias[l*32+co] = beta - mu*scale (0 for padded co / L9).
// ---------------------------------------------------------------------------
__global__ void prep_w(const float* __restrict__ w1, const float* __restrict__ w2,
                       const float* __restrict__ w3, const float* __restrict__ w4,
                       const float* __restrict__ g,  const float* __restrict__ be,
                       const float* __restrict__ mu, const float* __restrict__ va,
                       _Float16* __restrict__ wq, float* __restrict__ bias)
{
    const int FO[11]   = {0,576,1152,1728,2880,4032,5184,6336,7488,8640,8768};
    const int start[10]= {0,1080,2376,3672,8424,13608,16200,20952,26136,28728};
    const int COt[10]  = {12,12,12,24,24,12,24,24,12,11};
    const int CIt[10]  = {10,12,12,22,24,24,22,24,24,22};
    const int bnoff[10]= {0,12,24,36,60,84,96,120,144,0};
    const int KST[10]  = {1,1,1,2,2,2,2,2,2,2};

    long tid = (long)blockIdx.x * 256 + threadIdx.x;
    long total = (long)NB * 8768, stride = (long)gridDim.x * 256;
    for (long idx = tid; idx < total; idx += stride) {
        int b = (int)(idx / 8768), i = (int)(idx - (long)b * 8768);
        int l = 9; while (i < FO[l]) --l;
        int j = i - FO[l];
        int f = j >> 6, lane = j & 63;
        int ks = (KST[l] == 2) ? (f & 1) : 0;
        int s  = (KST[l] == 2) ? (f >> 1) : f;      // 3x3 tap index (0 for L9)
        int co = lane & 31, hi = lane >> 5;
        int CO = COt[l], CI = CIt[l];
        float scale = 1.f;
        if (l < 9 && co < CO) {
            int bi = bnoff[l] + co;
            scale = g[bi] * rsqrtf(va[bi] + EPSB);
        }
        int c0 = ks * 16 + hi * 8;
        __attribute__((aligned(16))) _Float16 vals[8];
#pragma unroll
        for (int e = 0; e < 8; ++e) {
            int c = c0 + e; float wv = 0.f;
            if (co < CO && c < CI) {
                int p = (l < 9) ? start[l] + (co * CI + c) * 9 + s
                                : start[9] + co * CI + c;
                const float* src; long si;
                if      (p <  3672) { src = w1; si = (long)b *  3672 + p; }
                else if (p < 16200) { src = w2; si = (long)b * 12528 + (p -  3672); }
                else if (p < 28728) { src = w3; si = (long)b * 12528 + (p - 16200); }
                else                { src = w4; si = (long)b *   242 + (p - 28728); }
                wv = src[si] * scale;
            }
            vals[e] = (_Float16)wv;
        }
        *(uh8*)(wq + idx * 8) = *(const h8*)vals;
    }
    if (tid < 320) {
        int l = (int)tid >> 5, co = (int)tid & 31;
        float v = 0.f;
        if (l < 9 && co < COt[l]) {
            int bi = bnoff[l] + co;
            float sc = g[bi] * rsqrtf(va[bi] + EPSB);
            v = be[bi] - mu[bi] * sc;
        }
        bias[tid] = v;
    }
}

// ---------------------------------------------------------------------------
// pad_x: init both NHWC 32-ch fp16 buffers for a chunk.
//   bufA: ch0-9 = x, ch10-11 = 0, ch12-21 = x, ch22-31 = 0  (stage1 input)
//   bufB: ch12-21 = x, rest 0                                (skip-concat copy)
// Borders and all unused channels zeroed.
// ---------------------------------------------------------------------------
__global__ void pad_x(const float* __restrict__ x, _Float16* __restrict__ bufA,
                      _Float16* __restrict__ bufB, int b0)
{
    int sl = blockIdx.x >> 3, part = blockIdx.x & 7;
    int gb = b0 + sl;
    const float* __restrict__ xs = x + (long)gb * 10 * HW;
    _Float16* __restrict__ dA = bufA + (long)sl * PXS * 32;
    _Float16* __restrict__ dB = bufB + (long)sl * PXS * 32;
    for (int p = part * 256 + threadIdx.x; p < PXS; p += 2048) {
        int r = p / W2, cc = p - r * W2;
        __attribute__((aligned(16))) _Float16 pxA[32], pxB[32];
#pragma unroll
        for (int i = 0; i < 32; ++i) { pxA[i] = (_Float16)0.f; pxB[i] = (_Float16)0.f; }
        if (r >= 1 && r <= 128 && cc >= 1 && cc <= 128) {
            int so = (r - 1) * 128 + (cc - 1);
#pragma unroll
            for (int c = 0; c < 10; ++c) {
                _Float16 xv = (_Float16)xs[c * HW + so];
                pxA[c] = xv; pxA[12 + c] = xv; pxB[12 + c] = xv;
            }
        }
        _Float16* ap = dA + (long)p * 32;
        _Float16* bp = dB + (long)p * 32;
#pragma unroll
        for (int q = 0; q < 4; ++q) {
            *(uh8*)(ap + q * 8) = *(const h8*)(pxA + q * 8);
            *(uh8*)(bp + q * 8) = *(const h8*)(pxB + q * 8);
        }
    }
}

// ---------------------------------------------------------------------------
// lconv: one 3x3 conv layer, LDS plane -> LDS plane (SoA granule layout).
// Plane = 3 granule-planes [ch-octet g][38*38 px] x 16B: lane-consecutive
// px -> consecutive 16B addresses -> conflict-free ds_read_b128/ds_write.
// All 30 reads of a unit share ONE VGPR base; offsets are compile-time
// immediates (ks*2*GPB + kc*16 + j*ROWB < 64K).
// Unit = NR output rows x 32 px; r0 clamped so every unit's NR rows are
// valid (tail units overlap-recompute identical rows -> benign).
// Register double-buffer: group g+1's B/A frags load during group g's MFMAs.
// Pad positions (outside global interior) stored as ZERO (reference padding).
// ---------------------------------------------------------------------------
template<int KST, int NR>
__device__ __forceinline__ void lconv(const char* pin, char* pout,
    const _Float16* wl, const float* __restrict__ bias, int boff,
    int rowStart, int nRows, int colStart, int width,
    int oy0, int ox0, int w, int lo5, int hi)
{
    constexpr int qmax = (KST == 1) ? 2 : 3;   // store ch0-15 / ch0-23
    f4 bv[qmax];
#pragma unroll
    for (int q = 0; q < qmax; ++q) bv[q] = *(const uf4*)(bias + boff + hi * 4 + q * 8);

    constexpr int NG = 3 * KST;
    const int ncb = (width > 32) ? 2 : 1;
    const int nrg = (nRows + NR - 1) / NR;
    const int nu  = nrg * ncb;
#pragma unroll 1
    for (int u = w; u < nu; u += NWV) {
        int rg, cb;
        if (ncb == 2) { rg = u >> 1; cb = u & 1; } else { rg = u; cb = 0; }
        int r0 = rowStart + rg * NR;
        { int rmax = rowStart + nRows - NR; r0 = (r0 > rmax) ? rmax : r0; }
        const int cs   = cb ? (colStart + width - 32) : colStart;
        const int cmin = cb ? (64 - width) : 0;
        // one base per unit; every read is base + compile-time offset
        const char* bin = pin + (long)hi * GPB
                        + ((long)(r0 - 1) * 38 + (cs - 1 + lo5)) * 16;

        f16v acc[NR];
        { f16v z = {};
#pragma unroll
          for (int i = 0; i < NR; ++i) acc[i] = z; }

        h8 bf[2][NR + 2];
        h8 af[2][3];
        // prologue: group 0 = (kc=0, ks=0) - never guarded (ks=0)
#pragma unroll
        for (int j = 0; j < NR + 2; ++j)
            bf[0][j] = *(const uh8*)(bin + j * ROWB);
#pragma unroll
        for (int kr = 0; kr < 3; ++kr)
            af[0][kr] = *(const uh8*)(wl + (kr * 3 * KST) * 512);

#pragma unroll
        for (int g = 0; g < NG; ++g) {
            const int cur = g & 1, nxt = cur ^ 1;
            if (g + 1 < NG) {                      // prefetch next group
                const int kc2 = (g + 1) / KST, ks2 = (g + 1) - kc2 * KST;
#pragma unroll
                for (int j = 0; j < NR + 2; ++j) {
                    h8 v = {};
                    if (!(ks2 & hi))               // granule 3 (ci24-31) = 0
                        v = *(const uh8*)(bin + ks2 * 2 * GPB + kc2 * 16 + j * ROWB);
                    bf[nxt][j] = v;
                }
#pragma unroll
                for (int kr = 0; kr < 3; ++kr)
                    af[nxt][kr] = *(const uh8*)(wl + ((kr * 3 + kc2) * KST + ks2) * 512);
            }
#pragma unroll
            for (int kr = 0; kr < 3; ++kr)
#pragma unroll
                for (int tt = 0; tt < NR; ++tt)
                    acc[tt] = __builtin_amdgcn_mfma_f32_32x32x16_f16(
                                  af[cur][kr], bf[cur][kr + tt], acc[tt], 0, 0, 0);
        }

        // epilogue: bias + ReLU + fp16 store (SoA granules, conflict-free)
        const bool cok = (lo5 >= cmin);
        const int  pc  = cs + lo5;
        const int  gx  = ox0 - 3 + pc;
        const bool xin = (unsigned)(gx - 1) < 128u;
        char* pob = pout + (long)hi * 8 + ((long)r0 * 38 + pc) * 16;
        if (cok) {
#pragma unroll
            for (int tt = 0; tt < NR; ++tt) {
                int gy = oy0 - 3 + r0 + tt;
                bool ok = xin && ((unsigned)(gy - 1) < 128u);
#pragma unroll
                for (int q = 0; q < qmax; ++q) {
                    float v0 = ok ? fmaxf(acc[tt][4*q+0] + bv[q][0], 0.f) : 0.f;
                    float v1 = ok ? fmaxf(acc[tt][4*q+1] + bv[q][1], 0.f) : 0.f;
                    float v2 = ok ? fmaxf(acc[tt][4*q+2] + bv[q][2], 0.f) : 0.f;
                    float v3 = ok ? fmaxf(acc[tt][4*q+3] + bv[q][3], 0.f) : 0.f;
                    h4 hv = { (_Float16)v0, (_Float16)v1, (_Float16)v2, (_Float16)v3 };
                    *(uh4*)(pob + q * GPB + tt * ROWB) = hv;
                }
            }
        }
    }
}

// ---------------------------------------------------------------------------
// stage3: fused 3-conv stage, 768 threads (12 waves, 3/SIMD; 1 block/CU due
// to 138.6KB LDS). Per block: one 32x32 output tile of one sample.
//  1) stage 38x38 px x ch0-23 from global NHWC (64B/px) into LDS plane S.
//     GLOBAL read order: granule fastest (c = idx%3) -> contiguous 48-of-64B
//     per pixel, consecutive px (R5 pattern, coalesced). LDS store order:
//     SoA granule planes (decoupled via registers; 2-way bank alias = free).
//  2) conv A: S->T (36x36), conv B: T->S (34x34), conv C: S->T (32x32),
//     all NR=3, barriers between.
//  3) write T's 32x32 interior, ch0-11 only, to global out (skip-concat:
//     x at ch12-21 of out buffer is preserved).
// ---------------------------------------------------------------------------
template<int KST>
__global__ __launch_bounds__(NTH)
void stage3(const _Float16* __restrict__ in, _Float16* __restrict__ out,
            const _Float16* __restrict__ wq, int loff0,
            const float* __restrict__ bias, int boff0, int b0)
{
    __shared__ _Float16 lds[2][PLH];
    const int t = threadIdx.x, w = t >> 6, l = t & 63;
    const int lo5 = l & 31, hi = l >> 5;

    const int nbb = (int)(gridDim.x >> 4);
    int s, tile;
    if ((nbb & 7) == 0) {                       // XCD-localize each sample
        int xcd = (int)(blockIdx.x & 7), j = (int)(blockIdx.x >> 3);
        s = xcd * (nbb >> 3) + (j >> 4); tile = j & 15;
    } else { s = (int)(blockIdx.x >> 4); tile = (int)(blockIdx.x & 15); }
    const int gb  = b0 + s;
    const int oy0 = 1 + (tile >> 2) * 32;       // padded-coord tile origin
    const int ox0 = 1 + (tile & 3) * 32;

    // ---- 1) stage input window: 4332 x 16B. Load coalesced (c fastest),
    //         store SoA (granule plane c, pixel p).
    {
        const char* src = (const char*)(in + (long)s * PXS * 32);
        char* dst = (char*)&lds[0][0];
        h8 stg[6];
#pragma unroll
        for (int k = 0; k < 6; ++k) {
            int idx = k * NTH + t;
            int p = idx / 3, c = idx - p * 3;
            int r = p / 38, cc = p - r * 38;
            int gy = oy0 - 3 + r, gx = ox0 - 3 + cc;
            h8 v = {};
            if (idx < 3 * GP && (unsigned)gy < 130u && (unsigned)gx < 130u)
                v = *(const uh8*)(src + ((long)gy * W2 + gx) * 64 + c * 16);
            stg[k] = v;
        }
#pragma unroll
        for (int k = 0; k < 6; ++k) {
            int idx = k * NTH + t;
            int p = idx / 3, c = idx - p * 3;
            if (idx < 3 * GP)
                *(uh8*)(dst + (long)c * GPB + (long)p * 16) = stg[k];
        }
    }
    __syncthreads();

    // ---- 2) three convs (regions 36 -> 34 -> 32)
    const _Float16* wl = wq + (long)gb * WQH + loff0 + (long)l * 8;
    constexpr int LSTEP = 9 * KST * 512;
    lconv<KST,3>((const char*)lds[0], (char*)lds[1], wl,             bias, boff0,      1, 36, 1, 36, oy0, ox0, w, lo5, hi);
    __syncthreads();
    lconv<KST,3>((const char*)lds[1], (char*)lds[0], wl + LSTEP,     bias, boff0 + 32, 2, 34, 2, 34, oy0, ox0, w, lo5, hi);
    __syncthreads();
    lconv<KST,3>((const char*)lds[0], (char*)lds[1], wl + 2 * LSTEP, bias, boff0 + 64, 3, 32, 3, 32, oy0, ox0, w, lo5, hi);
    __syncthreads();

    // ---- 3) write ch0-11 of the 32x32 interior to global
    {
        _Float16* db = out + (long)s * PXS * 32;
        const char* T = (const char*)&lds[1][0];
#pragma unroll
        for (int k = 0; k < 2; ++k) {
            int px = k * NTH + t;
            if (px < 1024) {
                int pr = 3 + (px >> 5), pc = 3 + (px & 31);
                int gy = oy0 + (px >> 5), gx = ox0 + (px & 31);
                const char* sp = T + ((long)pr * 38 + pc) * 16;
                h8 v0 = *(const uh8*)sp;            // ch0-7
                h4 v1 = *(const uh4*)(sp + GPB);    // ch8-11
                _Float16* dp = db + ((long)gy * W2 + gx) * 32;
                *(uh8*)dp = v0;
                *(uh4*)(dp + 8) = v1;
            }
        }
    }
}

// ---- final 1x1 conv (CIN=22 in bufB, CO=11), fp32 NCHW output, no BN/ReLU.
__global__ __launch_bounds__(256, 2)
void conv1(const _Float16* __restrict__ in, float* __restrict__ outF,
           const _Float16* __restrict__ wq, int loff, int b0)
{
    const int s = blockIdx.y, gb = b0 + s;
    const int t = threadIdx.x, w = t >> 6, l = t & 63;
    const int lo5 = l & 31, hi = l >> 5;
    const int cb = blockIdx.x & 3;
    const int y00 = (blockIdx.x >> 2) * 32 + w * 8;
    const int xpix = cb * 32 + lo5;

    const _Float16* wl = wq + (long)gb * WQH + loff + (long)l * 8;
    h8 a0 = *(const uh8*)(wl);
    h8 a1 = *(const uh8*)(wl + 512);
    const _Float16* ib = in + (long)s * PXS * 32;

#pragma unroll 1
    for (int tt = 0; tt < 8; ++tt) {
        int y = y00 + tt;
        const _Float16* bp = ib + ((long)(y + 1) * W2 + xpix + 1) * 32 + hi * 8;
        h8 bA = *(const uh8*)(bp);
        h8 bB = *(const uh8*)(bp + 16);
        f16v acc = {};
        acc = __builtin_amdgcn_mfma_f32_32x32x16_f16(a0, bA, acc, 0, 0, 0);
        acc = __builtin_amdgcn_mfma_f32_32x32x16_f16(a1, bB, acc, 0, 0, 0);
        long px = (long)y * 128 + xpix;
#pragma unroll
        for (int r = 0; r < 16; ++r) {
            int co = (r & 3) + 8 * (r >> 2) + 4 * hi;
            if (co < 11) outF[((long)gb * 11 + co) * HW + px] = acc[r];
        }
    }
}

extern "C" void kernel_launch(void* const* d_in, const int* in_sizes, int n_in,
                              void* d_out, int out_size, void* d_ws, size_t ws_size,
                              hipStream_t stream)
{
    const float *x = (const float*)d_in[0], *w1 = (const float*)d_in[1],
                *w2 = (const float*)d_in[2], *w3 = (const float*)d_in[3],
                *w4 = (const float*)d_in[4], *g  = (const float*)d_in[5],
                *be = (const float*)d_in[6], *mu = (const float*)d_in[7],
                *va = (const float*)d_in[8];
    if (n_in == 9) {   // identify by size signature (fallback: dict order)
        const float* big801[2] = {nullptr, nullptr}; int n801 = 0;
        const float* bn156[4]  = {nullptr, nullptr, nullptr, nullptr}; int n156 = 0;
        const float *fx = nullptr, *fw1 = nullptr, *fw4 = nullptr;
        for (int i = 0; i < 9; ++i) {
            int sz = in_sizes[i];
            if      (sz == 10485760) fx  = (const float*)d_in[i];
            else if (sz ==   235008) fw1 = (const float*)d_in[i];
            else if (sz ==   801792) { if (n801 < 2) big801[n801++] = (const float*)d_in[i]; }
            else if (sz ==    15488) fw4 = (const float*)d_in[i];
            else if (sz ==      156) { if (n156 < 4) bn156[n156++] = (const float*)d_in[i]; }
        }
        if (fx && fw1 && fw4 && n801 == 2 && n156 == 4) {
            x = fx; w1 = fw1; w2 = big801[0]; w3 = big801[1]; w4 = fw4;
            g = bn156[0]; be = bn156[1]; mu = bn156[2]; va = bn156[3];
        }
    }
    float* out = (float*)d_out;

    // ws: [wq fp16 8.98MB][bias 2KB][bufA | bufB], each 64B/px NHWC padded.
    // chunk=64 needs 9MB + 2*64*1.08MB = 147MB.
    const size_t wqB   = (size_t)NB * WQH * 2;
    const size_t biasB = 2048;
    const size_t hdr   = wqB + biasB;
    const size_t perSlot = (size_t)PXS * 128;   // 2 buffers x 64B/px
    size_t avail = ws_size > hdr ? ws_size - hdr : 0;
    int chunk = (int)(avail / perSlot);
    if (chunk > NB) chunk = NB;
    if (chunk < 1)  chunk = 1;

    _Float16* wq   = (_Float16*)d_ws;
    float*    bias = (float*)((char*)d_ws + wqB);
    _Float16* bufA = (_Float16*)((char*)d_ws + hdr);
    _Float16* bufB = bufA + (size_t)chunk * PXS * 32;

    prep_w<<<2048, 256, 0, stream>>>(w1, w2, w3, w4, g, be, mu, va, wq, bias);

    for (int b0 = 0; b0 < NB; b0 += chunk) {
        int nb = (NB - b0 < chunk) ? (NB - b0) : chunk;
        pad_x<<<nb * 8, 256, 0, stream>>>(x, bufA, bufB, b0);
        int gc = nb * 16;
        dim3 g1(16, nb);
        // stage1: L0-L2 (x @ bufA ch0-9) -> bufB ch0-11
        stage3<1><<<gc, NTH, 0, stream>>>(bufA, bufB, wq,     0, bias,   0, b0);
        // stage2: L3-L5 (bufB: prev@0-11 + x@12-21) -> bufA ch0-11
        stage3<2><<<gc, NTH, 0, stream>>>(bufB, bufA, wq, 13824, bias,  96, b0);
        // stage3: L6-L8 -> bufB ch0-11
        stage3<2><<<gc, NTH, 0, stream>>>(bufA, bufB, wq, 41472, bias, 192, b0);
        // L9: 1x1, 22ch -> 11ch fp32
        conv1<<<g1, 256, 0, stream>>>(bufB, out, wq, 69120, b0);
    }
}

// Round 8
// 466.488 us; speedup vs baseline: 1.1523x; 1.1371x over previous
//
#include <hip/hip_runtime.h>
#include <stdint.h>

#define HW    16384
#define NB    64
#define W2    130           // padded spatial dim (1-px halo each side)
#define PXS   (W2*W2)       // 16900 pixels per padded plane
#define WQH   70144         // fp16 weight halves per sample (frag-ordered)
#define EPSB  1e-5f
#define GP    1444          // px per LDS granule-plane (38*38)
#define GPB   23104         // bytes per granule-plane (GP*16)
#define ROWB  608           // bytes per row within a granule-plane (38*16)
#define PLH   34656         // halves per LDS plane (3 granules * 1444 * 8)
#define NTH   768           // stage3 threads (12 waves -> 3 waves/SIMD)
#define NWV   12

typedef _Float16 h8  __attribute__((ext_vector_type(8)));
typedef _Float16 h4  __attribute__((ext_vector_type(4)));
typedef float    f16v __attribute__((ext_vector_type(16)));
typedef float    f4  __attribute__((ext_vector_type(4)));
typedef h8 uh8 __attribute__((aligned(4)));
typedef h4 uh4 __attribute__((aligned(4)));
typedef f4 uf4 __attribute__((aligned(4)));

// ---------------------------------------------------------------------------
// prep_w: gather per-sample hypernet weights, fold BN scale, convert fp16,
// and write in EXACT mfma_32x32x16_f16 A-fragment order:
//   per layer, frame f = (tap*KST + kstep); within frame, lane(0..63) holds
//   8 halves: w[co = lane&31][c = kstep*16 + (lane>>5)*8 + e]  (0-padded).
// Frames/layer: L0-2: 9, L3-8: 18, L9(1x1): 2.
// Also emits fp32 bias[l*32+co] = beta - mu*scale (0 for padded co / L9).
// ---------------------------------------------------------------------------
__global__ void prep_w(const float* __restrict__ w1, const float* __restrict__ w2,
                       const float* __restrict__ w3, const float* __restrict__ w4,
                       const float* __restrict__ g,  const float* __restrict__ be,
                       const float* __restrict__ mu, const float* __restrict__ va,
                       _Float16* __restrict__ wq, float* __restrict__ bias)
{
    const int FO[11]   = {0,576,1152,1728,2880,4032,5184,6336,7488,8640,8768};
    const int start[10]= {0,1080,2376,3672,8424,13608,16200,20952,26136,28728};
    const int COt[10]  = {12,12,12,24,24,12,24,24,12,11};
    const int CIt[10]  = {10,12,12,22,24,24,22,24,24,22};
    const int bnoff[10]= {0,12,24,36,60,84,96,120,144,0};
    const int KST[10]  = {1,1,1,2,2,2,2,2,2,2};

    long tid = (long)blockIdx.x * 256 + threadIdx.x;
    long total = (long)NB * 8768, stride = (long)gridDim.x * 256;
    for (long idx = tid; idx < total; idx += stride) {
        int b = (int)(idx / 8768), i = (int)(idx - (long)b * 8768);
        int l = 9; while (i < FO[l]) --l;
        int j = i - FO[l];
        int f = j >> 6, lane = j & 63;
        int ks = (KST[l] == 2) ? (f & 1) : 0;
        int s  = (KST[l] == 2) ? (f >> 1) : f;      // 3x3 tap index (0 for L9)
        int co = lane & 31, hi = lane >> 5;
        int CO = COt[l], CI = CIt[l];
        float scale = 1.f;
        if (l < 9 && co < CO) {
            int bi = bnoff[l] + co;
            scale = g[bi] * rsqrtf(va[bi] + EPSB);
        }
        int c0 = ks * 16 + hi * 8;
        __attribute__((aligned(16))) _Float16 vals[8];
#pragma unroll
        for (int e = 0; e < 8; ++e) {
            int c = c0 + e; float wv = 0.f;
            if (co < CO && c < CI) {
                int p = (l < 9) ? start[l] + (co * CI + c) * 9 + s
                                : start[9] + co * CI + c;
                const float* src; long si;
                if      (p <  3672) { src = w1; si = (long)b *  3672 + p; }
                else if (p < 16200) { src = w2; si = (long)b * 12528 + (p -  3672); }
                else if (p < 28728) { src = w3; si = (long)b * 12528 + (p - 16200); }
                else                { src = w4; si = (long)b *   242 + (p - 28728); }
                wv = src[si] * scale;
            }
            vals[e] = (_Float16)wv;
        }
        *(uh8*)(wq + idx * 8) = *(const h8*)vals;
    }
    if (tid < 320) {
        int l = (int)tid >> 5, co = (int)tid & 31;
        float v = 0.f;
        if (l < 9 && co < COt[l]) {
            int bi = bnoff[l] + co;
            float sc = g[bi] * rsqrtf(va[bi] + EPSB);
            v = be[bi] - mu[bi] * sc;
        }
        bias[tid] = v;
    }
}

// ---------------------------------------------------------------------------
// pad_x: init both NHWC 32-ch fp16 buffers for a chunk.
//   bufA: ch0-9 = x, ch10-11 = 0, ch12-21 = x, ch22-31 = 0  (stage1 input)
//   bufB: ch12-21 = x, rest 0                                (skip-concat copy)
// Borders and all unused channels zeroed.
// ---------------------------------------------------------------------------
__global__ void pad_x(const float* __restrict__ x, _Float16* __restrict__ bufA,
                      _Float16* __restrict__ bufB, int b0)
{
    int sl = blockIdx.x >> 3, part = blockIdx.x & 7;
    int gb = b0 + sl;
    const float* __restrict__ xs = x + (long)gb * 10 * HW;
    _Float16* __restrict__ dA = bufA + (long)sl * PXS * 32;
    _Float16* __restrict__ dB = bufB + (long)sl * PXS * 32;
    for (int p = part * 256 + threadIdx.x; p < PXS; p += 2048) {
        int r = p / W2, cc = p - r * W2;
        __attribute__((aligned(16))) _Float16 pxA[32], pxB[32];
#pragma unroll
        for (int i = 0; i < 32; ++i) { pxA[i] = (_Float16)0.f; pxB[i] = (_Float16)0.f; }
        if (r >= 1 && r <= 128 && cc >= 1 && cc <= 128) {
            int so = (r - 1) * 128 + (cc - 1);
#pragma unroll
            for (int c = 0; c < 10; ++c) {
                _Float16 xv = (_Float16)xs[c * HW + so];
                pxA[c] = xv; pxA[12 + c] = xv; pxB[12 + c] = xv;
            }
        }
        _Float16* ap = dA + (long)p * 32;
        _Float16* bp = dB + (long)p * 32;
#pragma unroll
        for (int q = 0; q < 4; ++q) {
            *(uh8*)(ap + q * 8) = *(const h8*)(pxA + q * 8);
            *(uh8*)(bp + q * 8) = *(const h8*)(pxB + q * 8);
        }
    }
}

// ---------------------------------------------------------------------------
// lconv: one 3x3 conv layer, LDS plane -> LDS plane (SoA granule layout).
// Plane = 3 granule-planes [ch-octet g][38*38 px] x 16B: lane-consecutive
// px -> consecutive 16B addresses -> conflict-free ds_read_b128/ds_write.
// ROUND-8 RESTRUCTURE:
//   * afr[9*KST] A-fragments loaded from global ONCE PER LAYER into VGPRs
//     (R5-R7 re-read the full 18KB frag set per unit = 20x L2 re-read on the
//     vmcnt critical path). All units of the wave share them.
//   * manual register double-buffer removed (R6's VGPR=84 proved demotion;
//     single lgkm counter + compiler scheduling pipelines the 5 ds_reads
//     per group under the previous group's 9 MFMAs).
//   * bias loaded in the epilogue only (shrinks MFMA-phase live range).
// Unit = NR output rows x 32 px; r0 clamped so every unit's NR rows are
// valid (tail units overlap-recompute identical rows -> benign).
// Pad positions (outside global interior) stored as ZERO (reference padding).
// ---------------------------------------------------------------------------
template<int KST, int NR>
__device__ __forceinline__ void lconv(const char* pin, char* pout,
    const _Float16* wl, const float* __restrict__ bias, int boff,
    int rowStart, int nRows, int colStart, int width,
    int oy0, int ox0, int w, int lo5, int hi)
{
    constexpr int qmax = (KST == 1) ? 2 : 3;   // store ch0-15 / ch0-23
    constexpr int NG = 3 * KST;
    constexpr int FR = 9 * KST;

    // layer-wide A fragments: one-time global read, VGPR-resident
    h8 afr[FR];
#pragma unroll
    for (int f = 0; f < FR; ++f) afr[f] = *(const uh8*)(wl + (long)f * 512);

    const int ncb = (width > 32) ? 2 : 1;
    const int nrg = (nRows + NR - 1) / NR;
    const int nu  = nrg * ncb;
#pragma unroll 1
    for (int u = w; u < nu; u += NWV) {
        int rg, cb;
        if (ncb == 2) { rg = u >> 1; cb = u & 1; } else { rg = u; cb = 0; }
        int r0 = rowStart + rg * NR;
        { int rmax = rowStart + nRows - NR; r0 = (r0 > rmax) ? rmax : r0; }
        const int cs   = cb ? (colStart + width - 32) : colStart;
        const int cmin = cb ? (64 - width) : 0;
        // one base per unit; every read is base + compile-time offset
        const char* bin = pin + (long)hi * GPB
                        + ((long)(r0 - 1) * 38 + (cs - 1 + lo5)) * 16;

        f16v acc[NR];
        { f16v z = {};
#pragma unroll
          for (int i = 0; i < NR; ++i) acc[i] = z; }

#pragma unroll
        for (int g = 0; g < NG; ++g) {
            const int kc = g / KST, ks = g - kc * KST;
            h8 bf[NR + 2];
#pragma unroll
            for (int j = 0; j < NR + 2; ++j) {
                h8 v = {};
                if (!(ks & hi))                    // granule 3 (ci24-31) = 0
                    v = *(const uh8*)(bin + ks * 2 * GPB + kc * 16 + j * ROWB);
                bf[j] = v;
            }
#pragma unroll
            for (int kr = 0; kr < 3; ++kr)
#pragma unroll
                for (int tt = 0; tt < NR; ++tt)
                    acc[tt] = __builtin_amdgcn_mfma_f32_32x32x16_f16(
                                  afr[(kr * 3 + kc) * KST + ks], bf[kr + tt], acc[tt], 0, 0, 0);
        }

        // epilogue: bias + ReLU + fp16 store (SoA granules, conflict-free)
        f4 bv[qmax];
#pragma unroll
        for (int q = 0; q < qmax; ++q) bv[q] = *(const uf4*)(bias + boff + hi * 4 + q * 8);
        const bool cok = (lo5 >= cmin);
        const int  pc  = cs + lo5;
        const int  gx  = ox0 - 3 + pc;
        const bool xin = (unsigned)(gx - 1) < 128u;
        char* pob = pout + (long)hi * 8 + ((long)r0 * 38 + pc) * 16;
        if (cok) {
#pragma unroll
            for (int tt = 0; tt < NR; ++tt) {
                int gy = oy0 - 3 + r0 + tt;
                bool ok = xin && ((unsigned)(gy - 1) < 128u);
#pragma unroll
                for (int q = 0; q < qmax; ++q) {
                    float v0 = ok ? fmaxf(acc[tt][4*q+0] + bv[q][0], 0.f) : 0.f;
                    float v1 = ok ? fmaxf(acc[tt][4*q+1] + bv[q][1], 0.f) : 0.f;
                    float v2 = ok ? fmaxf(acc[tt][4*q+2] + bv[q][2], 0.f) : 0.f;
                    float v3 = ok ? fmaxf(acc[tt][4*q+3] + bv[q][3], 0.f) : 0.f;
                    h4 hv = { (_Float16)v0, (_Float16)v1, (_Float16)v2, (_Float16)v3 };
                    *(uh4*)(pob + q * GPB + tt * ROWB) = hv;
                }
            }
        }
    }
}

// ---------------------------------------------------------------------------
// stage3: fused 3-conv stage, 768 threads (12 waves, 3/SIMD; 1 block/CU due
// to 138.6KB LDS). Per block: one 32x32 output tile of one sample.
//  1) stage 38x38 px x ch0-23 from global NHWC (64B/px) into LDS plane S.
//     Coalesced load (c fastest); SoA store (granule plane c, pixel p).
//  2) conv A: S->T (36x36), conv B: T->S (34x34), conv C: S->T (32x32),
//     all NR=3 (A/B: 24 units = 2/wave exact; C: 11 units), barriers between.
//  3) write T's 32x32 interior, ch0-11 only, to global out (skip-concat:
//     x at ch12-21 of out buffer is preserved).
// ---------------------------------------------------------------------------
template<int KST>
__global__ __launch_bounds__(NTH)
void stage3(const _Float16* __restrict__ in, _Float16* __restrict__ out,
            const _Float16* __restrict__ wq, int loff0,
            const float* __restrict__ bias, int boff0, int b0)
{
    __shared__ _Float16 lds[2][PLH];
    const int t = threadIdx.x, w = t >> 6, l = t & 63;
    const int lo5 = l & 31, hi = l >> 5;

    const int nbb = (int)(gridDim.x >> 4);
    int s, tile;
    if ((nbb & 7) == 0) {                       // XCD-localize each sample
        int xcd = (int)(blockIdx.x & 7), j = (int)(blockIdx.x >> 3);
        s = xcd * (nbb >> 3) + (j >> 4); tile = j & 15;
    } else { s = (int)(blockIdx.x >> 4); tile = (int)(blockIdx.x & 15); }
    const int gb  = b0 + s;
    const int oy0 = 1 + (tile >> 2) * 32;       // padded-coord tile origin
    const int ox0 = 1 + (tile & 3) * 32;

    // ---- 1) stage input window: 4332 x 16B. Load coalesced (c fastest),
    //         store SoA (granule plane c, pixel p).
    {
        const char* src = (const char*)(in + (long)s * PXS * 32);
        char* dst = (char*)&lds[0][0];
        h8 stg[6];
#pragma unroll
        for (int k = 0; k < 6; ++k) {
            int idx = k * NTH + t;
            int p = idx / 3, c = idx - p * 3;
            int r = p / 38, cc = p - r * 38;
            int gy = oy0 - 3 + r, gx = ox0 - 3 + cc;
            h8 v = {};
            if (idx < 3 * GP && (unsigned)gy < 130u && (unsigned)gx < 130u)
                v = *(const uh8*)(src + ((long)gy * W2 + gx) * 64 + c * 16);
            stg[k] = v;
        }
#pragma unroll
        for (int k = 0; k < 6; ++k) {
            int idx = k * NTH + t;
            int p = idx / 3, c = idx - p * 3;
            if (idx < 3 * GP)
                *(uh8*)(dst + (long)c * GPB + (long)p * 16) = stg[k];
        }
    }
    __syncthreads();

    // ---- 2) three convs (regions 36 -> 34 -> 32)
    const _Float16* wl = wq + (long)gb * WQH + loff0 + (long)l * 8;
    constexpr int LSTEP = 9 * KST * 512;
    lconv<KST,3>((const char*)lds[0], (char*)lds[1], wl,             bias, boff0,      1, 36, 1, 36, oy0, ox0, w, lo5, hi);
    __syncthreads();
    lconv<KST,3>((const char*)lds[1], (char*)lds[0], wl + LSTEP,     bias, boff0 + 32, 2, 34, 2, 34, oy0, ox0, w, lo5, hi);
    __syncthreads();
    lconv<KST,3>((const char*)lds[0], (char*)lds[1], wl + 2 * LSTEP, bias, boff0 + 64, 3, 32, 3, 32, oy0, ox0, w, lo5, hi);
    __syncthreads();

    // ---- 3) write ch0-11 of the 32x32 interior to global
    {
        _Float16* db = out + (long)s * PXS * 32;
        const char* T = (const char*)&lds[1][0];
#pragma unroll
        for (int k = 0; k < 2; ++k) {
            int px = k * NTH + t;
            if (px < 1024) {
                int pr = 3 + (px >> 5), pc = 3 + (px & 31);
                int gy = oy0 + (px >> 5), gx = ox0 + (px & 31);
                const char* sp = T + ((long)pr * 38 + pc) * 16;
                h8 v0 = *(const uh8*)sp;            // ch0-7
                h4 v1 = *(const uh4*)(sp + GPB);    // ch8-11
                _Float16* dp = db + ((long)gy * W2 + gx) * 32;
                *(uh8*)dp = v0;
                *(uh4*)(dp + 8) = v1;
            }
        }
    }
}

// ---- final 1x1 conv (CIN=22 in bufB, CO=11), fp32 NCHW output, no BN/ReLU.
__global__ __launch_bounds__(256, 2)
void conv1(const _Float16* __restrict__ in, float* __restrict__ outF,
           const _Float16* __restrict__ wq, int loff, int b0)
{
    const int s = blockIdx.y, gb = b0 + s;
    const int t = threadIdx.x, w = t >> 6, l = t & 63;
    const int lo5 = l & 31, hi = l >> 5;
    const int cb = blockIdx.x & 3;
    const int y00 = (blockIdx.x >> 2) * 32 + w * 8;
    const int xpix = cb * 32 + lo5;

    const _Float16* wl = wq + (long)gb * WQH + loff + (long)l * 8;
    h8 a0 = *(const uh8*)(wl);
    h8 a1 = *(const uh8*)(wl + 512);
    const _Float16* ib = in + (long)s * PXS * 32;

#pragma unroll 1
    for (int tt = 0; tt < 8; ++tt) {
        int y = y00 + tt;
        const _Float16* bp = ib + ((long)(y + 1) * W2 + xpix + 1) * 32 + hi * 8;
        h8 bA = *(const uh8*)(bp);
        h8 bB = *(const uh8*)(bp + 16);
        f16v acc = {};
        acc = __builtin_amdgcn_mfma_f32_32x32x16_f16(a0, bA, acc, 0, 0, 0);
        acc = __builtin_amdgcn_mfma_f32_32x32x16_f16(a1, bB, acc, 0, 0, 0);
        long px = (long)y * 128 + xpix;
#pragma unroll
        for (int r = 0; r < 16; ++r) {
            int co = (r & 3) + 8 * (r >> 2) + 4 * hi;
            if (co < 11) outF[((long)gb * 11 + co) * HW + px] = acc[r];
        }
    }
}

extern "C" void kernel_launch(void* const* d_in, const int* in_sizes, int n_in,
                              void* d_out, int out_size, void* d_ws, size_t ws_size,
                              hipStream_t stream)
{
    const float *x = (const float*)d_in[0], *w1 = (const float*)d_in[1],
                *w2 = (const float*)d_in[2], *w3 = (const float*)d_in[3],
                *w4 = (const float*)d_in[4], *g  = (const float*)d_in[5],
                *be = (const float*)d_in[6], *mu = (const float*)d_in[7],
                *va = (const float*)d_in[8];
    if (n_in == 9) {   // identify by size signature (fallback: dict order)
        const float* big801[2] = {nullptr, nullptr}; int n801 = 0;
        const float* bn156[4]  = {nullptr, nullptr, nullptr, nullptr}; int n156 = 0;
        const float *fx = nullptr, *fw1 = nullptr, *fw4 = nullptr;
        for (int i = 0; i < 9; ++i) {
            int sz = in_sizes[i];
            if      (sz == 10485760) fx  = (const float*)d_in[i];
            else if (sz ==   235008) fw1 = (const float*)d_in[i];
            else if (sz ==   801792) { if (n801 < 2) big801[n801++] = (const float*)d_in[i]; }
            else if (sz ==    15488) fw4 = (const float*)d_in[i];
            else if (sz ==      156) { if (n156 < 4) bn156[n156++] = (const float*)d_in[i]; }
        }
        if (fx && fw1 && fw4 && n801 == 2 && n156 == 4) {
            x = fx; w1 = fw1; w2 = big801[0]; w3 = big801[1]; w4 = fw4;
            g = bn156[0]; be = bn156[1]; mu = bn156[2]; va = bn156[3];
        }
    }
    float* out = (float*)d_out;

    // ws: [wq fp16 8.98MB][bias 2KB][bufA | bufB], each 64B/px NHWC padded.
    // chunk=64 needs 9MB + 2*64*1.08MB = 147MB.
    const size_t wqB   = (size_t)NB * WQH * 2;
    const size_t biasB = 2048;
    const size_t hdr   = wqB + biasB;
    const size_t perSlot = (size_t)PXS * 128;   // 2 buffers x 64B/px
    size_t avail = ws_size > hdr ? ws_size - hdr : 0;
    int chunk = (int)(avail / perSlot);
    if (chunk > NB) chunk = NB;
    if (chunk < 1)  chunk = 1;

    _Float16* wq   = (_Float16*)d_ws;
    float*    bias = (float*)((char*)d_ws + wqB);
    _Float16* bufA = (_Float16*)((char*)d_ws + hdr);
    _Float16* bufB = bufA + (size_t)chunk * PXS * 32;

    prep_w<<<2048, 256, 0, stream>>>(w1, w2, w3, w4, g, be, mu, va, wq, bias);

    for (int b0 = 0; b0 < NB; b0 += chunk) {
        int nb = (NB - b0 < chunk) ? (NB - b0) : chunk;
        pad_x<<<nb * 8, 256, 0, stream>>>(x, bufA, bufB, b0);
        int gc = nb * 16;
        dim3 g1(16, nb);
        // stage1: L0-L2 (x @ bufA ch0-9) -> bufB ch0-11
        stage3<1><<<gc, NTH, 0, stream>>>(bufA, bufB, wq,     0, bias,   0, b0);
        // stage2: L3-L5 (bufB: prev@0-11 + x@12-21) -> bufA ch0-11
        stage3<2><<<gc, NTH, 0, stream>>>(bufB, bufA, wq, 13824, bias,  96, b0);
        // stage3: L6-L8 -> bufB ch0-11
        stage3<2><<<gc, NTH, 0, stream>>>(bufA, bufB, wq, 41472, bias, 192, b0);
        // L9: 1x1, 22ch -> 11ch fp32
        conv1<<<g1, 256, 0, stream>>>(bufB, out, wq, 69120, b0);
    }
}

// Round 9
// 461.120 us; speedup vs baseline: 1.1658x; 1.0116x over previous
//
#include <hip/hip_runtime.h>
#include <stdint.h>

#define HW    16384
#define NB    64
#define W2    130           // padded spatial dim (1-px halo each side)
#define PXS   (W2*W2)       // 16900 pixels per padded plane
#define WQH   70144         // fp16 weight halves per sample (frag-ordered)
#define EPSB  1e-5f
#define GP    1444          // px per LDS granule-plane (38*38)
#define GPB   23104         // bytes per granule-plane (GP*16)
#define ROWB  608           // bytes per row within a granule-plane (38*16)
#define ZPB   2560          // zero-scratch bytes (>= kc*16 + 4*ROWB = 2464)

typedef _Float16 h8  __attribute__((ext_vector_type(8)));
typedef _Float16 h4  __attribute__((ext_vector_type(4)));
typedef float    f16v __attribute__((ext_vector_type(16)));
typedef float    f4  __attribute__((ext_vector_type(4)));
typedef h8 uh8 __attribute__((aligned(4)));
typedef h4 uh4 __attribute__((aligned(4)));
typedef f4 uf4 __attribute__((aligned(4)));

// ---------------------------------------------------------------------------
// prep_w: gather per-sample hypernet weights, fold BN scale, convert fp16,
// and write in EXACT mfma_32x32x16_f16 A-fragment order:
//   per layer, frame f = (tap*KST + kstep); within frame, lane(0..63) holds
//   8 halves: w[co = lane&31][c = kstep*16 + (lane>>5)*8 + e]  (0-padded).
// Frames/layer: L0-2: 9, L3-8: 18, L9(1x1): 2.
// Also emits fp32 bias[l*32+co] = beta - mu*scale (0 for padded co / L9).
// ---------------------------------------------------------------------------
__global__ void prep_w(const float* __restrict__ w1, const float* __restrict__ w2,
                       const float* __restrict__ w3, const float* __restrict__ w4,
                       const float* __restrict__ g,  const float* __restrict__ be,
                       const float* __restrict__ mu, const float* __restrict__ va,
                       _Float16* __restrict__ wq, float* __restrict__ bias)
{
    const int FO[11]   = {0,576,1152,1728,2880,4032,5184,6336,7488,8640,8768};
    const int start[10]= {0,1080,2376,3672,8424,13608,16200,20952,26136,28728};
    const int COt[10]  = {12,12,12,24,24,12,24,24,12,11};
    const int CIt[10]  = {10,12,12,22,24,24,22,24,24,22};
    const int bnoff[10]= {0,12,24,36,60,84,96,120,144,0};
    const int KST[10]  = {1,1,1,2,2,2,2,2,2,2};

    long tid = (long)blockIdx.x * 256 + threadIdx.x;
    long total = (long)NB * 8768, stride = (long)gridDim.x * 256;
    for (long idx = tid; idx < total; idx += stride) {
        int b = (int)(idx / 8768), i = (int)(idx - (long)b * 8768);
        int l = 9; while (i < FO[l]) --l;
        int j = i - FO[l];
        int f = j >> 6, lane = j & 63;
        int ks = (KST[l] == 2) ? (f & 1) : 0;
        int s  = (KST[l] == 2) ? (f >> 1) : f;      // 3x3 tap index (0 for L9)
        int co = lane & 31, hi = lane >> 5;
        int CO = COt[l], CI = CIt[l];
        float scale = 1.f;
        if (l < 9 && co < CO) {
            int bi = bnoff[l] + co;
            scale = g[bi] * rsqrtf(va[bi] + EPSB);
        }
        int c0 = ks * 16 + hi * 8;
        __attribute__((aligned(16))) _Float16 vals[8];
#pragma unroll
        for (int e = 0; e < 8; ++e) {
            int c = c0 + e; float wv = 0.f;
            if (co < CO && c < CI) {
                int p = (l < 9) ? start[l] + (co * CI + c) * 9 + s
                                : start[9] + co * CI + c;
                const float* src; long si;
                if      (p <  3672) { src = w1; si = (long)b *  3672 + p; }
                else if (p < 16200) { src = w2; si = (long)b * 12528 + (p -  3672); }
                else if (p < 28728) { src = w3; si = (long)b * 12528 + (p - 16200); }
                else                { src = w4; si = (long)b *   242 + (p - 28728); }
                wv = src[si] * scale;
            }
            vals[e] = (_Float16)wv;
        }
        *(uh8*)(wq + idx * 8) = *(const h8*)vals;
    }
    if (tid < 320) {
        int l = (int)tid >> 5, co = (int)tid & 31;
        float v = 0.f;
        if (l < 9 && co < COt[l]) {
            int bi = bnoff[l] + co;
            float sc = g[bi] * rsqrtf(va[bi] + EPSB);
            v = be[bi] - mu[bi] * sc;
        }
        bias[tid] = v;
    }
}

// ---------------------------------------------------------------------------
// pad_x: init both NHWC 32-ch fp16 buffers for a chunk.
//   bufA: ch0-9 = x, ch10-11 = 0, ch12-21 = x, ch22-31 = 0  (stage1 input)
//   bufB: ch12-21 = x, rest 0                                (skip-concat copy)
// Borders and all unused channels zeroed.
// ---------------------------------------------------------------------------
__global__ void pad_x(const float* __restrict__ x, _Float16* __restrict__ bufA,
                      _Float16* __restrict__ bufB, int b0)
{
    int sl = blockIdx.x >> 3, part = blockIdx.x & 7;
    int gb = b0 + sl;
    const float* __restrict__ xs = x + (long)gb * 10 * HW;
    _Float16* __restrict__ dA = bufA + (long)sl * PXS * 32;
    _Float16* __restrict__ dB = bufB + (long)sl * PXS * 32;
    for (int p = part * 256 + threadIdx.x; p < PXS; p += 2048) {
        int r = p / W2, cc = p - r * W2;
        __attribute__((aligned(16))) _Float16 pxA[32], pxB[32];
#pragma unroll
        for (int i = 0; i < 32; ++i) { pxA[i] = (_Float16)0.f; pxB[i] = (_Float16)0.f; }
        if (r >= 1 && r <= 128 && cc >= 1 && cc <= 128) {
            int so = (r - 1) * 128 + (cc - 1);
#pragma unroll
            for (int c = 0; c < 10; ++c) {
                _Float16 xv = (_Float16)xs[c * HW + so];
                pxA[c] = xv; pxA[12 + c] = xv; pxB[12 + c] = xv;
            }
        }
        _Float16* ap = dA + (long)p * 32;
        _Float16* bp = dB + (long)p * 32;
#pragma unroll
        for (int q = 0; q < 4; ++q) {
            *(uh8*)(ap + q * 8) = *(const h8*)(pxA + q * 8);
            *(uh8*)(bp + q * 8) = *(const h8*)(pxB + q * 8);
        }
    }
}

// ---------------------------------------------------------------------------
// lconv: one 3x3 conv layer, LDS plane -> LDS plane (SoA granule layout).
// Plane = NGR granule-planes [ch-octet g][38*38 px] x 16B: lane-consecutive
// px -> consecutive 16B addresses -> conflict-free ds_read_b128/ds_write.
// afr[9*KST] A-fragments global->reg ONCE PER LAYER (R8 win: no per-unit
// re-read). REV template: odd waves run the commuting (kc,ks) groups in
// reverse order -> de-phases the per-SIMD LDS-burst / MFMA-burst collisions
// of barrier-locked waves. s_setprio(1) wraps the MFMA nest (T5).
// ks=1 reads: hi=1 lanes (nonexistent ci24-31) take a cndmask'd base into a
// zeroed LDS scratch (broadcast reads) instead of exec-masked loads + 4
// zero-movs per frag (~60 VALU/unit saved).
// Unit = NR output rows x 32 px; r0 clamped (tail overlap-recompute benign).
// Pad positions (outside global interior) stored as ZERO (reference padding).
// ---------------------------------------------------------------------------
template<int KST, int NR, int TNWV, bool REV>
__device__ __forceinline__ void lconv(const char* pin, char* pout,
    const char* zbase,
    const _Float16* wl, const float* __restrict__ bias, int boff,
    int rowStart, int nRows, int colStart, int width,
    int oy0, int ox0, int w, int lo5, int hi)
{
    constexpr int qmax = (KST == 1) ? 2 : 3;   // store ch0-15 / ch0-23
    constexpr int NG = 3 * KST;
    constexpr int FR = 9 * KST;

    // layer-wide A fragments: one-time global read, register-resident
    h8 afr[FR];
#pragma unroll
    for (int f = 0; f < FR; ++f) afr[f] = *(const uh8*)(wl + (long)f * 512);

    const int ncb = (width > 32) ? 2 : 1;
    const int nrg = (nRows + NR - 1) / NR;
    const int nu  = nrg * ncb;
#pragma unroll 1
    for (int u = w; u < nu; u += TNWV) {
        int rg, cb;
        if (ncb == 2) { rg = u >> 1; cb = u & 1; } else { rg = u; cb = 0; }
        int r0 = rowStart + rg * NR;
        { int rmax = rowStart + nRows - NR; r0 = (r0 > rmax) ? rmax : r0; }
        const int cs   = cb ? (colStart + width - 32) : colStart;
        const int cmin = cb ? (64 - width) : 0;
        // one base per unit; every read is base + compile-time offset
        const char* bin = pin + (long)hi * GPB
                        + ((long)(r0 - 1) * 38 + (cs - 1 + lo5)) * 16;
        const char* binH = bin + 2 * GPB;          // ks=1 source (real data)
        if (KST == 2 && hi) binH = zbase;          // ci24-31 -> zero scratch

        f16v acc[NR];
        { f16v z = {};
#pragma unroll
          for (int i = 0; i < NR; ++i) acc[i] = z; }

#pragma unroll
        for (int gg = 0; gg < NG; ++gg) {
            const int g  = REV ? (NG - 1 - gg) : gg;
            const int kc = g / KST, ks = g - kc * KST;
            const char* base = ks ? binH : bin;
            h8 bf[NR + 2];
#pragma unroll
            for (int j = 0; j < NR + 2; ++j)
                bf[j] = *(const uh8*)(base + kc * 16 + j * ROWB);
            __builtin_amdgcn_s_setprio(1);
#pragma unroll
            for (int kr = 0; kr < 3; ++kr)
#pragma unroll
                for (int tt = 0; tt < NR; ++tt)
                    acc[tt] = __builtin_amdgcn_mfma_f32_32x32x16_f16(
                                  afr[(kr * 3 + kc) * KST + ks], bf[kr + tt], acc[tt], 0, 0, 0);
            __builtin_amdgcn_s_setprio(0);
        }

        // epilogue: bias + ReLU + fp16 store (SoA granules, conflict-free)
        f4 bv[qmax];
#pragma unroll
        for (int q = 0; q < qmax; ++q) bv[q] = *(const uf4*)(bias + boff + hi * 4 + q * 8);
        const bool cok = (lo5 >= cmin);
        const int  pc  = cs + lo5;
        const int  gx  = ox0 - 3 + pc;
        const bool xin = (unsigned)(gx - 1) < 128u;
        char* pob = pout + (long)hi * 8 + ((long)r0 * 38 + pc) * 16;
        if (cok) {
#pragma unroll
            for (int tt = 0; tt < NR; ++tt) {
                int gy = oy0 - 3 + r0 + tt;
                bool ok = xin && ((unsigned)(gy - 1) < 128u);
#pragma unroll
                for (int q = 0; q < qmax; ++q) {
                    float v0 = ok ? fmaxf(acc[tt][4*q+0] + bv[q][0], 0.f) : 0.f;
                    float v1 = ok ? fmaxf(acc[tt][4*q+1] + bv[q][1], 0.f) : 0.f;
                    float v2 = ok ? fmaxf(acc[tt][4*q+2] + bv[q][2], 0.f) : 0.f;
                    float v3 = ok ? fmaxf(acc[tt][4*q+3] + bv[q][3], 0.f) : 0.f;
                    h4 hv = { (_Float16)v0, (_Float16)v1, (_Float16)v2, (_Float16)v3 };
                    *(uh4*)(pob + q * GPB + tt * ROWB) = hv;
                }
            }
        }
    }
}

// ---------------------------------------------------------------------------
// stage3: fused 3-conv stage. Per block: one 32x32 output tile of one sample.
//   KST=1 (stage1): 2-granule planes (ch0-15 only ever touched) -> LDS
//     92.4KB; TNTH=1024 (16 waves, 4/SIMD; afr only 36 regs, bounds-capped).
//   KST=2 (stage2/3): 3-granule planes, 138.6KB + 2.5KB zero scratch;
//     TNTH=768 (12 waves, 3/SIMD; ~155 total regs incl AGPR-held afr).
//  1) stage 38x38 px x NGR granules from global NHWC (coalesced load,
//     SoA store); zero the ks=1 scratch (KST=2).
//  2) conv A: S->T (36x36), conv B: T->S (34x34), conv C: S->T (32x32),
//     NR=3, barriers between; odd waves REV group order (de-phase).
//  3) write T's 32x32 interior, ch0-11 only, to global out (skip-concat:
//     x at ch12-21 of out buffer is preserved).
// ---------------------------------------------------------------------------
template<int KST, int TNTH>
__global__ __launch_bounds__(TNTH)
void stage3(const _Float16* __restrict__ in, _Float16* __restrict__ out,
            const _Float16* __restrict__ wq, int loff0,
            const float* __restrict__ bias, int boff0, int b0)
{
    constexpr int NGR  = (KST == 1) ? 2 : 3;
    constexpr int PLHk = NGR * GP * 8;          // halves per plane
    constexpr int TNWV = TNTH / 64;
    __shared__ _Float16 lds[2][PLHk];
    __shared__ char zpad[(KST == 2) ? ZPB : 16];

    const int t = threadIdx.x, w = t >> 6, l = t & 63;
    const int lo5 = l & 31, hi = l >> 5;

    const int nbb = (int)(gridDim.x >> 4);
    int s, tile;
    if ((nbb & 7) == 0) {                       // XCD-localize each sample
        int xcd = (int)(blockIdx.x & 7), j = (int)(blockIdx.x >> 3);
        s = xcd * (nbb >> 3) + (j >> 4); tile = j & 15;
    } else { s = (int)(blockIdx.x >> 4); tile = (int)(blockIdx.x & 15); }
    const int gb  = b0 + s;
    const int oy0 = 1 + (tile >> 2) * 32;       // padded-coord tile origin
    const int ox0 = 1 + (tile & 3) * 32;

    // ---- 1) stage input window: NGR*1444 x 16B. Load coalesced (c fastest),
    //         store SoA (granule plane c, pixel p). Zero the ks=1 scratch.
    {
        constexpr int NLD = NGR * GP;
        constexpr int SI  = (NLD + TNTH - 1) / TNTH;
        const char* src = (const char*)(in + (long)s * PXS * 32);
        char* dst = (char*)&lds[0][0];
        h8 stg[SI];
#pragma unroll
        for (int k = 0; k < SI; ++k) {
            int idx = k * TNTH + t;
            int p = idx / NGR, c = idx - p * NGR;
            int r = p / 38, cc = p - r * 38;
            int gy = oy0 - 3 + r, gx = ox0 - 3 + cc;
            h8 v = {};
            if (idx < NLD && (unsigned)gy < 130u && (unsigned)gx < 130u)
                v = *(const uh8*)(src + ((long)gy * W2 + gx) * 64 + c * 16);
            stg[k] = v;
        }
#pragma unroll
        for (int k = 0; k < SI; ++k) {
            int idx = k * TNTH + t;
            int p = idx / NGR, c = idx - p * NGR;
            if (idx < NLD)
                *(uh8*)(dst + (long)c * GPB + (long)p * 16) = stg[k];
        }
        if (KST == 2 && t < ZPB / 16) {
            h8 z = {};
            *(uh8*)(zpad + t * 16) = z;
        }
    }
    __syncthreads();

    // ---- 2) three convs (regions 36 -> 34 -> 32); odd waves reverse group
    //         order to de-phase LDS/MFMA bursts across the SIMD's waves.
    const _Float16* wl = wq + (long)gb * WQH + loff0 + (long)l * 8;
    const char* zb = (const char*)zpad;
    constexpr int LSTEP = 9 * KST * 512;
#define LCONV(PIN, POUT, WOFF, BOFF, RS, NRW, CS, WD)                          \
    if (w & 1) lconv<KST,3,TNWV,true >((const char*)(PIN), (char*)(POUT), zb,  \
        wl + (WOFF), bias, boff0 + (BOFF), RS, NRW, CS, WD, oy0, ox0, w, lo5, hi); \
    else       lconv<KST,3,TNWV,false>((const char*)(PIN), (char*)(POUT), zb,  \
        wl + (WOFF), bias, boff0 + (BOFF), RS, NRW, CS, WD, oy0, ox0, w, lo5, hi);

    LCONV(lds[0], lds[1], 0,         0,  1, 36, 1, 36);
    __syncthreads();
    LCONV(lds[1], lds[0], LSTEP,     32, 2, 34, 2, 34);
    __syncthreads();
    LCONV(lds[0], lds[1], 2 * LSTEP, 64, 3, 32, 3, 32);
    __syncthreads();
#undef LCONV

    // ---- 3) write ch0-11 of the 32x32 interior to global
    {
        _Float16* db = out + (long)s * PXS * 32;
        const char* T = (const char*)&lds[1][0];
        constexpr int WB = (1024 + TNTH - 1) / TNTH;
#pragma unroll
        for (int k = 0; k < WB; ++k) {
            int px = k * TNTH + t;
            if (px < 1024) {
                int pr = 3 + (px >> 5), pc = 3 + (px & 31);
                int gy = oy0 + (px >> 5), gx = ox0 + (px & 31);
                const char* sp = T + ((long)pr * 38 + pc) * 16;
                h8 v0 = *(const uh8*)sp;            // ch0-7
                h4 v1 = *(const uh4*)(sp + GPB);    // ch8-11
                _Float16* dp = db + ((long)gy * W2 + gx) * 32;
                *(uh8*)dp = v0;
                *(uh4*)(dp + 8) = v1;
            }
        }
    }
}

// ---- final 1x1 conv (CIN=22 in bufB, CO=11), fp32 NCHW output, no BN/ReLU.
__global__ __launch_bounds__(256, 2)
void conv1(const _Float16* __restrict__ in, float* __restrict__ outF,
           const _Float16* __restrict__ wq, int loff, int b0)
{
    const int s = blockIdx.y, gb = b0 + s;
    const int t = threadIdx.x, w = t >> 6, l = t & 63;
    const int lo5 = l & 31, hi = l >> 5;
    const int cb = blockIdx.x & 3;
    const int y00 = (blockIdx.x >> 2) * 32 + w * 8;
    const int xpix = cb * 32 + lo5;

    const _Float16* wl = wq + (long)gb * WQH + loff + (long)l * 8;
    h8 a0 = *(const uh8*)(wl);
    h8 a1 = *(const uh8*)(wl + 512);
    const _Float16* ib = in + (long)s * PXS * 32;

#pragma unroll 1
    for (int tt = 0; tt < 8; ++tt) {
        int y = y00 + tt;
        const _Float16* bp = ib + ((long)(y + 1) * W2 + xpix + 1) * 32 + hi * 8;
        h8 bA = *(const uh8*)(bp);
        h8 bB = *(const uh8*)(bp + 16);
        f16v acc = {};
        acc = __builtin_amdgcn_mfma_f32_32x32x16_f16(a0, bA, acc, 0, 0, 0);
        acc = __builtin_amdgcn_mfma_f32_32x32x16_f16(a1, bB, acc, 0, 0, 0);
        long px = (long)y * 128 + xpix;
#pragma unroll
        for (int r = 0; r < 16; ++r) {
            int co = (r & 3) + 8 * (r >> 2) + 4 * hi;
            if (co < 11) outF[((long)gb * 11 + co) * HW + px] = acc[r];
        }
    }
}

extern "C" void kernel_launch(void* const* d_in, const int* in_sizes, int n_in,
                              void* d_out, int out_size, void* d_ws, size_t ws_size,
                              hipStream_t stream)
{
    const float *x = (const float*)d_in[0], *w1 = (const float*)d_in[1],
                *w2 = (const float*)d_in[2], *w3 = (const float*)d_in[3],
                *w4 = (const float*)d_in[4], *g  = (const float*)d_in[5],
                *be = (const float*)d_in[6], *mu = (const float*)d_in[7],
                *va = (const float*)d_in[8];
    if (n_in == 9) {   // identify by size signature (fallback: dict order)
        const float* big801[2] = {nullptr, nullptr}; int n801 = 0;
        const float* bn156[4]  = {nullptr, nullptr, nullptr, nullptr}; int n156 = 0;
        const float *fx = nullptr, *fw1 = nullptr, *fw4 = nullptr;
        for (int i = 0; i < 9; ++i) {
            int sz = in_sizes[i];
            if      (sz == 10485760) fx  = (const float*)d_in[i];
            else if (sz ==   235008) fw1 = (const float*)d_in[i];
            else if (sz ==   801792) { if (n801 < 2) big801[n801++] = (const float*)d_in[i]; }
            else if (sz ==    15488) fw4 = (const float*)d_in[i];
            else if (sz ==      156) { if (n156 < 4) bn156[n156++] = (const float*)d_in[i]; }
        }
        if (fx && fw1 && fw4 && n801 == 2 && n156 == 4) {
            x = fx; w1 = fw1; w2 = big801[0]; w3 = big801[1]; w4 = fw4;
            g = bn156[0]; be = bn156[1]; mu = bn156[2]; va = bn156[3];
        }
    }
    float* out = (float*)d_out;

    // ws: [wq fp16 8.98MB][bias 2KB][bufA | bufB], each 64B/px NHWC padded.
    // chunk=64 needs 9MB + 2*64*1.08MB = 147MB.
    const size_t wqB   = (size_t)NB * WQH * 2;
    const size_t biasB = 2048;
    const size_t hdr   = wqB + biasB;
    const size_t perSlot = (size_t)PXS * 128;   // 2 buffers x 64B/px
    size_t avail = ws_size > hdr ? ws_size - hdr : 0;
    int chunk = (int)(avail / perSlot);
    if (chunk > NB) chunk = NB;
    if (chunk < 1)  chunk = 1;

    _Float16* wq   = (_Float16*)d_ws;
    float*    bias = (float*)((char*)d_ws + wqB);
    _Float16* bufA = (_Float16*)((char*)d_ws + hdr);
    _Float16* bufB = bufA + (size_t)chunk * PXS * 32;

    prep_w<<<2048, 256, 0, stream>>>(w1, w2, w3, w4, g, be, mu, va, wq, bias);

    for (int b0 = 0; b0 < NB; b0 += chunk) {
        int nb = (NB - b0 < chunk) ? (NB - b0) : chunk;
        pad_x<<<nb * 8, 256, 0, stream>>>(x, bufA, bufB, b0);
        int gc = nb * 16;
        dim3 g1(16, nb);
        // stage1: L0-L2 (x @ bufA ch0-9) -> bufB ch0-11  (1024 thr, 16 waves)
        stage3<1,1024><<<gc, 1024, 0, stream>>>(bufA, bufB, wq,     0, bias,   0, b0);
        // stage2: L3-L5 (bufB: prev@0-11 + x@12-21) -> bufA ch0-11
        stage3<2, 768><<<gc,  768, 0, stream>>>(bufB, bufA, wq, 13824, bias,  96, b0);
        // stage3: L6-L8 -> bufB ch0-11
        stage3<2, 768><<<gc,  768, 0, stream>>>(bufA, bufB, wq, 41472, bias, 192, b0);
        // L9: 1x1, 22ch -> 11ch fp32
        conv1<<<g1, 256, 0, stream>>>(bufB, out, wq, 69120, b0);
    }
}

// Round 10
// 439.869 us; speedup vs baseline: 1.2221x; 1.0483x over previous
//
#include <hip/hip_runtime.h>
#include <stdint.h>

#define HW    16384
#define NB    64
#define W2    130           // padded spatial dim (1-px halo each side)
#define PXS   (W2*W2)       // 16900 pixels per padded plane
#define WQH   70144         // fp16 weight halves per sample (frag-ordered)
#define EPSB  1e-5f
#define WCOL  70            // LDS window cols (64 tile + 2*3 halo)
#define WROW  22            // LDS window rows (16 tile + 2*3 halo)
#define GP    (WROW*WCOL)   // px per LDS granule-plane (1540)
#define GPB   (GP*16)       // bytes per granule-plane (24640)
#define ROWB  (WCOL*16)     // bytes per row within a granule-plane (1120)
#define ZPB   4608          // zero-scratch bytes (>= kc*16 + 4*ROWB = 4512)

typedef _Float16 h8  __attribute__((ext_vector_type(8)));
typedef _Float16 h4  __attribute__((ext_vector_type(4)));
typedef float    f16v __attribute__((ext_vector_type(16)));
typedef float    f4  __attribute__((ext_vector_type(4)));
typedef h8 uh8 __attribute__((aligned(4)));
typedef h4 uh4 __attribute__((aligned(4)));
typedef f4 uf4 __attribute__((aligned(4)));

// ---------------------------------------------------------------------------
// prep_w: gather per-sample hypernet weights, fold BN scale, convert fp16,
// and write in EXACT mfma_32x32x16_f16 A-fragment order:
//   per layer, frame f = (tap*KST + kstep); within frame, lane(0..63) holds
//   8 halves: w[co = lane&31][c = kstep*16 + (lane>>5)*8 + e]  (0-padded).
// Frames/layer: L0-2: 9, L3-8: 18, L9(1x1): 2.
// Also emits fp32 bias[l*32+co] = beta - mu*scale (0 for padded co / L9).
// ---------------------------------------------------------------------------
__global__ void prep_w(const float* __restrict__ w1, const float* __restrict__ w2,
                       const float* __restrict__ w3, const float* __restrict__ w4,
                       const float* __restrict__ g,  const float* __restrict__ be,
                       const float* __restrict__ mu, const float* __restrict__ va,
                       _Float16* __restrict__ wq, float* __restrict__ bias)
{
    const int FO[11]   = {0,576,1152,1728,2880,4032,5184,6336,7488,8640,8768};
    const int start[10]= {0,1080,2376,3672,8424,13608,16200,20952,26136,28728};
    const int COt[10]  = {12,12,12,24,24,12,24,24,12,11};
    const int CIt[10]  = {10,12,12,22,24,24,22,24,24,22};
    const int bnoff[10]= {0,12,24,36,60,84,96,120,144,0};
    const int KST[10]  = {1,1,1,2,2,2,2,2,2,2};

    long tid = (long)blockIdx.x * 256 + threadIdx.x;
    long total = (long)NB * 8768, stride = (long)gridDim.x * 256;
    for (long idx = tid; idx < total; idx += stride) {
        int b = (int)(idx / 8768), i = (int)(idx - (long)b * 8768);
        int l = 9; while (i < FO[l]) --l;
        int j = i - FO[l];
        int f = j >> 6, lane = j & 63;
        int ks = (KST[l] == 2) ? (f & 1) : 0;
        int s  = (KST[l] == 2) ? (f >> 1) : f;      // 3x3 tap index (0 for L9)
        int co = lane & 31, hi = lane >> 5;
        int CO = COt[l], CI = CIt[l];
        float scale = 1.f;
        if (l < 9 && co < CO) {
            int bi = bnoff[l] + co;
            scale = g[bi] * rsqrtf(va[bi] + EPSB);
        }
        int c0 = ks * 16 + hi * 8;
        __attribute__((aligned(16))) _Float16 vals[8];
#pragma unroll
        for (int e = 0; e < 8; ++e) {
            int c = c0 + e; float wv = 0.f;
            if (co < CO && c < CI) {
                int p = (l < 9) ? start[l] + (co * CI + c) * 9 + s
                                : start[9] + co * CI + c;
                const float* src; long si;
                if      (p <  3672) { src = w1; si = (long)b *  3672 + p; }
                else if (p < 16200) { src = w2; si = (long)b * 12528 + (p -  3672); }
                else if (p < 28728) { src = w3; si = (long)b * 12528 + (p - 16200); }
                else                { src = w4; si = (long)b *   242 + (p - 28728); }
                wv = src[si] * scale;
            }
            vals[e] = (_Float16)wv;
        }
        *(uh8*)(wq + idx * 8) = *(const h8*)vals;
    }
    if (tid < 320) {
        int l = (int)tid >> 5, co = (int)tid & 31;
        float v = 0.f;
        if (l < 9 && co < COt[l]) {
            int bi = bnoff[l] + co;
            float sc = g[bi] * rsqrtf(va[bi] + EPSB);
            v = be[bi] - mu[bi] * sc;
        }
        bias[tid] = v;
    }
}

// ---------------------------------------------------------------------------
// pad_x: init both NHWC 32-ch fp16 buffers for a chunk.
//   bufA: ch0-9 = x, ch10-11 = 0, ch12-21 = x, ch22-31 = 0  (stage1 input)
//   bufB: ch12-21 = x, rest 0                                (skip-concat copy)
// Borders and all unused channels zeroed.
// ---------------------------------------------------------------------------
__global__ void pad_x(const float* __restrict__ x, _Float16* __restrict__ bufA,
                      _Float16* __restrict__ bufB, int b0)
{
    int sl = blockIdx.x >> 3, part = blockIdx.x & 7;
    int gb = b0 + sl;
    const float* __restrict__ xs = x + (long)gb * 10 * HW;
    _Float16* __restrict__ dA = bufA + (long)sl * PXS * 32;
    _Float16* __restrict__ dB = bufB + (long)sl * PXS * 32;
    for (int p = part * 256 + threadIdx.x; p < PXS; p += 2048) {
        int r = p / W2, cc = p - r * W2;
        __attribute__((aligned(16))) _Float16 pxA[32], pxB[32];
#pragma unroll
        for (int i = 0; i < 32; ++i) { pxA[i] = (_Float16)0.f; pxB[i] = (_Float16)0.f; }
        if (r >= 1 && r <= 128 && cc >= 1 && cc <= 128) {
            int so = (r - 1) * 128 + (cc - 1);
#pragma unroll
            for (int c = 0; c < 10; ++c) {
                _Float16 xv = (_Float16)xs[c * HW + so];
                pxA[c] = xv; pxA[12 + c] = xv; pxB[12 + c] = xv;
            }
        }
        _Float16* ap = dA + (long)p * 32;
        _Float16* bp = dB + (long)p * 32;
#pragma unroll
        for (int q = 0; q < 4; ++q) {
            *(uh8*)(ap + q * 8) = *(const h8*)(pxA + q * 8);
            *(uh8*)(bp + q * 8) = *(const h8*)(pxB + q * 8);
        }
    }
}

// ---------------------------------------------------------------------------
// lconv: one 3x3 conv layer, LDS plane -> LDS plane (SoA granule layout).
// Plane = NGR granule-planes [ch-octet g][22*70 px] x 16B: lane-consecutive
// px -> consecutive 16B addresses -> conflict-free ds_read_b128/ds_write.
// afr[9*KST] A-fragments global->reg ONCE PER LAYER (R8 win). ks=1/hi=1
// lanes (nonexistent ci24-31) read a zeroed LDS scratch via cndmask'd base.
// Unit = NR output rows x one 32-px col-block; ncb = ceil(width/32) blocks,
// the LAST block is rightmost-32 (stores lanes lo5 >= ncb*32-width).
// 64x16 tile => width 68/66/64: col efficiency 71/69/100% (vs 56/53/100% at
// the old 32-wide tile) -- 13.5% less MFMA+LDS work per output px.
// r0 clamped (tail overlap-recompute benign). Pad positions (outside global
// interior) stored as ZERO (reference padding). setprio(1) wraps MFMAs (T5).
// ---------------------------------------------------------------------------
template<int KST, int NR, int TNWV>
__device__ __forceinline__ void lconv(const char* pin, char* pout,
    const char* zbase,
    const _Float16* wl, const float* __restrict__ bias, int boff,
    int rowStart, int nRows, int colStart, int width,
    int oy0, int ox0, int w, int lo5, int hi)
{
    constexpr int qmax = (KST == 1) ? 2 : 3;   // store ch0-15 / ch0-23
    constexpr int NG = 3 * KST;
    constexpr int FR = 9 * KST;

    // layer-wide A fragments: one-time global read, register-resident
    h8 afr[FR];
#pragma unroll
    for (int f = 0; f < FR; ++f) afr[f] = *(const uh8*)(wl + (long)f * 512);

    const int ncb = (width + 31) >> 5;
    const int nrg = (nRows + NR - 1) / NR;
    const int nu  = nrg * ncb;
#pragma unroll 1
    for (int u = w; u < nu; u += TNWV) {
        const int rg = u / ncb, cb = u - rg * ncb;
        int r0 = rowStart + rg * NR;
        { int rmax = rowStart + nRows - NR; r0 = (r0 > rmax) ? rmax : r0; }
        const bool last = (cb == ncb - 1);
        const int cs   = last ? (colStart + width - 32) : (colStart + cb * 32);
        const int cmin = last ? (ncb * 32 - width) : 0;
        // one base per unit; every read is base + compile-time offset
        const char* bin = pin + (long)hi * GPB
                        + ((long)(r0 - 1) * WCOL + (cs - 1 + lo5)) * 16;
        const char* binH = bin + 2 * GPB;          // ks=1 source (real data)
        if (KST == 2 && hi) binH = zbase;          // ci24-31 -> zero scratch

        f16v acc[NR];
        { f16v z = {};
#pragma unroll
          for (int i = 0; i < NR; ++i) acc[i] = z; }

#pragma unroll
        for (int g = 0; g < NG; ++g) {
            const int kc = g / KST, ks = g - kc * KST;
            const char* base = ks ? binH : bin;
            h8 bf[NR + 2];
#pragma unroll
            for (int j = 0; j < NR + 2; ++j)
                bf[j] = *(const uh8*)(base + kc * 16 + j * ROWB);
            __builtin_amdgcn_s_setprio(1);
#pragma unroll
            for (int kr = 0; kr < 3; ++kr)
#pragma unroll
                for (int tt = 0; tt < NR; ++tt)
                    acc[tt] = __builtin_amdgcn_mfma_f32_32x32x16_f16(
                                  afr[(kr * 3 + kc) * KST + ks], bf[kr + tt], acc[tt], 0, 0, 0);
            __builtin_amdgcn_s_setprio(0);
        }

        // epilogue: bias + ReLU + fp16 store (SoA granules, conflict-free)
        f4 bv[qmax];
#pragma unroll
        for (int q = 0; q < qmax; ++q) bv[q] = *(const uf4*)(bias + boff + hi * 4 + q * 8);
        const bool cok = (lo5 >= cmin);
        const int  pc  = cs + lo5;
        const int  gx  = ox0 - 3 + pc;
        const bool xin = (unsigned)(gx - 1) < 128u;
        char* pob = pout + (long)hi * 8 + ((long)r0 * WCOL + pc) * 16;
        if (cok) {
#pragma unroll
            for (int tt = 0; tt < NR; ++tt) {
                int gy = oy0 - 3 + r0 + tt;
                bool ok = xin && ((unsigned)(gy - 1) < 128u);
#pragma unroll
                for (int q = 0; q < qmax; ++q) {
                    float v0 = ok ? fmaxf(acc[tt][4*q+0] + bv[q][0], 0.f) : 0.f;
                    float v1 = ok ? fmaxf(acc[tt][4*q+1] + bv[q][1], 0.f) : 0.f;
                    float v2 = ok ? fmaxf(acc[tt][4*q+2] + bv[q][2], 0.f) : 0.f;
                    float v3 = ok ? fmaxf(acc[tt][4*q+3] + bv[q][3], 0.f) : 0.f;
                    h4 hv = { (_Float16)v0, (_Float16)v1, (_Float16)v2, (_Float16)v3 };
                    *(uh4*)(pob + q * GPB + tt * ROWB) = hv;
                }
            }
        }
    }
}

// ---------------------------------------------------------------------------
// stage3: fused 3-conv stage. Per block: one 64x16 output tile of one sample
// (16 tiles/sample: 2 col-tiles x 8 row-tiles).
//   KST=1 (stage1): 2-granule planes (ch0-15), LDS 98.6KB, TNTH=1024.
//   KST=2 (stage2/3): 3-granule planes, 147.8KB + 4.5KB scratch, TNTH=768.
//  1) stage 22x70 px x NGR granules from global NHWC (coalesced load,
//     SoA store); zero the ks=1 scratch (KST=2).
//  2) conv A: S->T (20x68), conv B: T->S (18x66), conv C: S->T (16x64),
//     NR=3, barriers between.
//  3) write T's 16x64 interior, ch0-11 only, to global out (skip-concat:
//     x at ch12-21 of out buffer is preserved).
// ---------------------------------------------------------------------------
template<int KST, int TNTH>
__global__ __launch_bounds__(TNTH)
void stage3(const _Float16* __restrict__ in, _Float16* __restrict__ out,
            const _Float16* __restrict__ wq, int loff0,
            const float* __restrict__ bias, int boff0, int b0)
{
    constexpr int NGR  = (KST == 1) ? 2 : 3;
    constexpr int PLHk = NGR * GP * 8;          // halves per plane
    constexpr int TNWV = TNTH / 64;
    __shared__ _Float16 lds[2][PLHk];
    __shared__ char zpad[(KST == 2) ? ZPB : 16];

    const int t = threadIdx.x, w = t >> 6, l = t & 63;
    const int lo5 = l & 31, hi = l >> 5;

    const int nbb = (int)(gridDim.x >> 4);
    int s, tile;
    if ((nbb & 7) == 0) {                       // XCD-localize each sample
        int xcd = (int)(blockIdx.x & 7), j = (int)(blockIdx.x >> 3);
        s = xcd * (nbb >> 3) + (j >> 4); tile = j & 15;
    } else { s = (int)(blockIdx.x >> 4); tile = (int)(blockIdx.x & 15); }
    const int gb  = b0 + s;
    const int oy0 = 1 + (tile >> 1) * 16;       // padded-coord tile origin
    const int ox0 = 1 + (tile & 1) * 64;

    // ---- 1) stage input window: NGR*1540 x 16B. Load coalesced (c fastest),
    //         store SoA (granule plane c, pixel p). Zero the ks=1 scratch.
    {
        constexpr int NLD = NGR * GP;
        constexpr int SI  = (NLD + TNTH - 1) / TNTH;
        const char* src = (const char*)(in + (long)s * PXS * 32);
        char* dst = (char*)&lds[0][0];
        h8 stg[SI];
#pragma unroll
        for (int k = 0; k < SI; ++k) {
            int idx = k * TNTH + t;
            int p = idx / NGR, c = idx - p * NGR;
            int r = p / WCOL, cc = p - r * WCOL;
            int gy = oy0 - 3 + r, gx = ox0 - 3 + cc;
            h8 v = {};
            if (idx < NLD && (unsigned)gy < 130u && (unsigned)gx < 130u)
                v = *(const uh8*)(src + ((long)gy * W2 + gx) * 64 + c * 16);
            stg[k] = v;
        }
#pragma unroll
        for (int k = 0; k < SI; ++k) {
            int idx = k * TNTH + t;
            int p = idx / NGR, c = idx - p * NGR;
            if (idx < NLD)
                *(uh8*)(dst + (long)c * GPB + (long)p * 16) = stg[k];
        }
        if (KST == 2 && t < ZPB / 16) {
            h8 z = {};
            *(uh8*)(zpad + t * 16) = z;
        }
    }
    __syncthreads();

    // ---- 2) three convs (regions 20x68 -> 18x66 -> 16x64)
    const _Float16* wl = wq + (long)gb * WQH + loff0 + (long)l * 8;
    const char* zb = (const char*)zpad;
    constexpr int LSTEP = 9 * KST * 512;
    lconv<KST,3,TNWV>((const char*)lds[0], (char*)lds[1], zb, wl,
                      bias, boff0,      1, 20, 1, 68, oy0, ox0, w, lo5, hi);
    __syncthreads();
    lconv<KST,3,TNWV>((const char*)lds[1], (char*)lds[0], zb, wl + LSTEP,
                      bias, boff0 + 32, 2, 18, 2, 66, oy0, ox0, w, lo5, hi);
    __syncthreads();
    lconv<KST,3,TNWV>((const char*)lds[0], (char*)lds[1], zb, wl + 2 * LSTEP,
                      bias, boff0 + 64, 3, 16, 3, 64, oy0, ox0, w, lo5, hi);
    __syncthreads();

    // ---- 3) write ch0-11 of the 16x64 interior to global
    {
        _Float16* db = out + (long)s * PXS * 32;
        const char* T = (const char*)&lds[1][0];
        constexpr int WB = (1024 + TNTH - 1) / TNTH;
#pragma unroll
        for (int k = 0; k < WB; ++k) {
            int px = k * TNTH + t;
            if (px < 1024) {
                int pr = 3 + (px >> 6), pc = 3 + (px & 63);
                int gy = oy0 + (px >> 6), gx = ox0 + (px & 63);
                const char* sp = T + ((long)pr * WCOL + pc) * 16;
                h8 v0 = *(const uh8*)sp;            // ch0-7
                h4 v1 = *(const uh4*)(sp + GPB);    // ch8-11
                _Float16* dp = db + ((long)gy * W2 + gx) * 32;
                *(uh8*)dp = v0;
                *(uh4*)(dp + 8) = v1;
            }
        }
    }
}

// ---- final 1x1 conv (CIN=22 in bufB, CO=11), fp32 NCHW output, no BN/ReLU.
__global__ __launch_bounds__(256, 2)
void conv1(const _Float16* __restrict__ in, float* __restrict__ outF,
           const _Float16* __restrict__ wq, int loff, int b0)
{
    const int s = blockIdx.y, gb = b0 + s;
    const int t = threadIdx.x, w = t >> 6, l = t & 63;
    const int lo5 = l & 31, hi = l >> 5;
    const int cb = blockIdx.x & 3;
    const int y00 = (blockIdx.x >> 2) * 32 + w * 8;
    const int xpix = cb * 32 + lo5;

    const _Float16* wl = wq + (long)gb * WQH + loff + (long)l * 8;
    h8 a0 = *(const uh8*)(wl);
    h8 a1 = *(const uh8*)(wl + 512);
    const _Float16* ib = in + (long)s * PXS * 32;

#pragma unroll 1
    for (int tt = 0; tt < 8; ++tt) {
        int y = y00 + tt;
        const _Float16* bp = ib + ((long)(y + 1) * W2 + xpix + 1) * 32 + hi * 8;
        h8 bA = *(const uh8*)(bp);
        h8 bB = *(const uh8*)(bp + 16);
        f16v acc = {};
        acc = __builtin_amdgcn_mfma_f32_32x32x16_f16(a0, bA, acc, 0, 0, 0);
        acc = __builtin_amdgcn_mfma_f32_32x32x16_f16(a1, bB, acc, 0, 0, 0);
        long px = (long)y * 128 + xpix;
#pragma unroll
        for (int r = 0; r < 16; ++r) {
            int co = (r & 3) + 8 * (r >> 2) + 4 * hi;
            if (co < 11) outF[((long)gb * 11 + co) * HW + px] = acc[r];
        }
    }
}

extern "C" void kernel_launch(void* const* d_in, const int* in_sizes, int n_in,
                              void* d_out, int out_size, void* d_ws, size_t ws_size,
                              hipStream_t stream)
{
    const float *x = (const float*)d_in[0], *w1 = (const float*)d_in[1],
                *w2 = (const float*)d_in[2], *w3 = (const float*)d_in[3],
                *w4 = (const float*)d_in[4], *g  = (const float*)d_in[5],
                *be = (const float*)d_in[6], *mu = (const float*)d_in[7],
                *va = (const float*)d_in[8];
    if (n_in == 9) {   // identify by size signature (fallback: dict order)
        const float* big801[2] = {nullptr, nullptr}; int n801 = 0;
        const float* bn156[4]  = {nullptr, nullptr, nullptr, nullptr}; int n156 = 0;
        const float *fx = nullptr, *fw1 = nullptr, *fw4 = nullptr;
        for (int i = 0; i < 9; ++i) {
            int sz = in_sizes[i];
            if      (sz == 10485760) fx  = (const float*)d_in[i];
            else if (sz ==   235008) fw1 = (const float*)d_in[i];
            else if (sz ==   801792) { if (n801 < 2) big801[n801++] = (const float*)d_in[i]; }
            else if (sz ==    15488) fw4 = (const float*)d_in[i];
            else if (sz ==      156) { if (n156 < 4) bn156[n156++] = (const float*)d_in[i]; }
        }
        if (fx && fw1 && fw4 && n801 == 2 && n156 == 4) {
            x = fx; w1 = fw1; w2 = big801[0]; w3 = big801[1]; w4 = fw4;
            g = bn156[0]; be = bn156[1]; mu = bn156[2]; va = bn156[3];
        }
    }
    float* out = (float*)d_out;

    // ws: [wq fp16 8.98MB][bias 2KB][bufA | bufB], each 64B/px NHWC padded.
    // chunk=64 needs 9MB + 2*64*1.08MB = 147MB.
    const size_t wqB   = (size_t)NB * WQH * 2;
    const size_t biasB = 2048;
    const size_t hdr   = wqB + biasB;
    const size_t perSlot = (size_t)PXS * 128;   // 2 buffers x 64B/px
    size_t avail = ws_size > hdr ? ws_size - hdr : 0;
    int chunk = (int)(avail / perSlot);
    if (chunk > NB) chunk = NB;
    if (chunk < 1)  chunk = 1;

    _Float16* wq   = (_Float16*)d_ws;
    float*    bias = (float*)((char*)d_ws + wqB);
    _Float16* bufA = (_Float16*)((char*)d_ws + hdr);
    _Float16* bufB = bufA + (size_t)chunk * PXS * 32;

    prep_w<<<2048, 256, 0, stream>>>(w1, w2, w3, w4, g, be, mu, va, wq, bias);

    for (int b0 = 0; b0 < NB; b0 += chunk) {
        int nb = (NB - b0 < chunk) ? (NB - b0) : chunk;
        pad_x<<<nb * 8, 256, 0, stream>>>(x, bufA, bufB, b0);
        int gc = nb * 16;
        dim3 g1(16, nb);
        // stage1: L0-L2 (x @ bufA ch0-9) -> bufB ch0-11  (1024 thr, 16 waves)
        stage3<1,1024><<<gc, 1024, 0, stream>>>(bufA, bufB, wq,     0, bias,   0, b0);
        // stage2: L3-L5 (bufB: prev@0-11 + x@12-21) -> bufA ch0-11
        stage3<2, 768><<<gc,  768, 0, stream>>>(bufB, bufA, wq, 13824, bias,  96, b0);
        // stage3: L6-L8 -> bufB ch0-11
        stage3<2, 768><<<gc,  768, 0, stream>>>(bufA, bufB, wq, 41472, bias, 192, b0);
        // L9: 1x1, 22ch -> 11ch fp32
        conv1<<<g1, 256, 0, stream>>>(bufB, out, wq, 69120, b0);
    }
}